// Round 8
// baseline (316.055 us; speedup 1.0000x reference)
//
#include <hip/hip_runtime.h>
#include <hip/hip_fp16.h>

// RipEncoding, round 8: arithmetic offp (no divergent constant loads),
// packed-fp16 accumulation, hoisted per-level address math, fused 3-launch
// height pooling.
//
// ws layout: [0, 332928000) fp16 pyramid (10 verts x 1020x1020 px x 16 halfs)
//            [332928000, +41943040) float4 proj table [v][n] = (cx,cy,lx,ly)

#define NV 10
#define FD 16
#define NS 262144          // 2^18
#define PYR_PX 1040400L    // 1020*1020 pixels per vertex
#define PYR_BYTES 332928000L

__constant__ float c_P[NV][2][3] = {
  {{-0.7071067811865476f, 0.7071067811865476f, 0.0f},
   {-0.4082482904638631f,-0.4082482904638631f, 0.8164965809277261f}},
  {{-0.7071067811865476f, 0.7071067811865476f, 0.0f},
   { 0.4082482904638631f, 0.4082482904638631f, 0.8164965809277261f}},
  {{ 0.7071067811865476f, 0.7071067811865476f, 0.0f},
   {-0.4082482904638631f, 0.4082482904638631f, 0.8164965809277261f}},
  {{ 0.7071067811865476f, 0.7071067811865476f, 0.0f},
   { 0.4082482904638631f,-0.4082482904638631f, 0.8164965809277261f}},
  {{-1.0f, 0.0f, 0.0f},
   { 0.0f,-0.3568220897730899f, 0.9341723589627157f}},
  {{-1.0f, 0.0f, 0.0f},
   { 0.0f, 0.3568220897730899f, 0.9341723589627157f}},
  {{ 0.0f, 1.0f, 0.0f},
   {-0.9341723589627157f, 0.0f, 0.3568220897730899f}},
  {{ 0.0f, 1.0f, 0.0f},
   { 0.9341723589627157f, 0.0f, 0.3568220897730899f}},
  {{-0.3568220897730899f, 0.9341723589627157f, 0.0f},
   { 0.0f, 0.0f, 1.0f}},
  {{ 0.3568220897730899f, 0.9341723589627157f, 0.0f},
   { 0.0f, 0.0f, 1.0f}},
};

__constant__ int c_CW[8] = {0, 512, 768, 896, 960, 992, 1008, 1016};

// arithmetic plane offset: CW[l] = 1024 - (1024>>l)
// offp(l1,l2) = 1020*CW[l1] + (512>>l1)*CW[l2]
__device__ __forceinline__ int offp_a(int l1, int l2) {
  return 1044480 - (1020 << (10 - l1)) + ((1024 - (1024 >> l2)) << (9 - l1));
}
// compile-time variant for build_w (l1 constant there)
__device__ __forceinline__ long offp(int l1, int l2) {
  return 1020L * (long)c_CW[l1] + (long)(512 >> l1) * (long)c_CW[l2];
}

__device__ __forceinline__ uint2 pack4(float4 f) {
  __half2 h0 = __floats2half2_rn(f.x, f.y);
  __half2 h1 = __floats2half2_rn(f.z, f.w);
  uint2 s;
  s.x = *(unsigned int*)&h0;
  s.y = *(unsigned int*)&h1;
  return s;
}

// ---- pass 1: one block per (v, y) row; all 8 width levels from LDS ----
__global__ __launch_bounds__(256) void build_w(const float* __restrict__ fm,
                                               __half* __restrict__ pyr)
{
  __shared__ float4 lds[512 * 5];   // pixel p, quad fb at lds[p*5+fb]; 40 KB
  int b = blockIdx.x;
  int v = b >> 9, y = b & 511;
  int t = threadIdx.x;
  const float4* src = (const float4*)(fm + ((long)v * 262144L + (long)y * 512) * FD);
  #pragma unroll
  for (int i = 0; i < 8; ++i) {
    int u = t + 256 * i;                        // linear float4 index 0..2047
    float4 d = src[u];
    lds[(u >> 2) * 5 + (u & 3)] = d;
  }
  __syncthreads();
  __half* bv = pyr + (long)v * PYR_PX * FD;
  {                                             // level (0,0): convert row
    uint2* dst = (uint2*)(bv + (long)y * 512 * FD);
    #pragma unroll
    for (int i = 0; i < 8; ++i) {
      int u = t + 256 * i;
      dst[u] = pack4(lds[(u >> 2) * 5 + (u & 3)]);
    }
  }
  #pragma unroll
  for (int l1 = 1; l1 <= 7; ++l1) {
    int W = 512 >> l1;
    int units = W * 4;
    float4 r[4];
    #pragma unroll
    for (int i = 0; i < 4; ++i) {
      int u = t + 256 * i;
      if (u < units) {
        int px = u >> 2, fb = u & 3;
        float4 a = lds[(2 * px) * 5 + fb];
        float4 c = lds[(2 * px + 1) * 5 + fb];
        r[i].x = 0.5f * (a.x + c.x); r[i].y = 0.5f * (a.y + c.y);
        r[i].z = 0.5f * (a.z + c.z); r[i].w = 0.5f * (a.w + c.w);
      }
    }
    __syncthreads();
    uint2* dst = (uint2*)(bv + (offp(l1, 0) + (long)y * W) * FD);
    #pragma unroll
    for (int i = 0; i < 4; ++i) {
      int u = t + 256 * i;
      if (u < units) {
        int px = u >> 2, fb = u & 3;
        lds[px * 5 + fb] = r[i];
        dst[u] = pack4(r[i]);
      }
    }
    __syncthreads();
  }
}

// ---- pass 2: fused height pools. Each thread reads 2^NLEV rows of level
// (l1, L2SRC) at one 16B slot and emits levels L2SRC+1 .. L2SRC+NLEV. ----
template<int L2SRC, int NLEV>
__global__ __launch_bounds__(256) void pool_hN(__half* __restrict__ pyr)
{
  constexpr int R = 1 << NLEV;
  constexpr int HL = 512 >> (L2SRC + NLEV);     // rows of the last level
  int total = NV * HL * 2040;
  int t = blockIdx.x * 256 + threadIdx.x;
  if (t >= total) return;
  int u = t % 2040;
  int r2 = t / 2040;
  int c = u >> 1, k = u & 1;          // virtual column, 16B slot
  int y = r2 % HL;
  int v = r2 / HL;
  int l1 = 0;
  #pragma unroll
  for (int i = 1; i < 8; ++i) l1 += (c >= c_CW[i]) ? 1 : 0;
  int x = c - c_CW[l1];
  int W = 512 >> l1;
  __half* bv = pyr + (long)v * PYR_PX * FD;
  const __half* src = bv + (long)offp_a(l1, L2SRC) * FD;

  uint4 d[R];
  long base = ((long)(y * R) * W + x) * FD + k * 8;
  #pragma unroll
  for (int r = 0; r < R; ++r)
    d[r] = *(const uint4*)(src + base + (long)r * W * FD);

  const __half2 hhalf = __floats2half2_rn(0.5f, 0.5f);
  #pragma unroll
  for (int lev = 1; lev <= NLEV; ++lev) {
    int cnt = R >> lev;
    __half* dst = bv + (long)offp_a(l1, L2SRC + lev) * FD;
    #pragma unroll
    for (int r = 0; r < cnt; ++r) {
      const __half2* a = (const __half2*)&d[2 * r];
      const __half2* b = (const __half2*)&d[2 * r + 1];
      uint4 res;
      __half2* rr = (__half2*)&res;
      #pragma unroll
      for (int j = 0; j < 4; ++j)
        rr[j] = __hmul2(__hadd2(a[j], b[j]), hhalf);
      d[r] = res;
      *(uint4*)(dst + (((long)(y * cnt + r)) * W + x) * FD + k * 8) = res;
    }
  }
}

// ---- projection/level precompute: one thread per sample ----
__global__ __launch_bounds__(256) void proj_kernel(const float* __restrict__ means,
                                                   const float* __restrict__ covs,
                                                   float4* __restrict__ pl)
{
  int n = blockIdx.x * 256 + threadIdx.x;
  if (n >= NS) return;
  float m0 = means[3 * n], m1 = means[3 * n + 1], m2 = means[3 * n + 2];
  const float* C = covs + 9L * n;
  float c0 = C[0], c1 = C[1], c2 = C[2];
  float c3 = C[3], c4 = C[4], c5 = C[5];
  float c6 = C[6], c7 = C[7], c8 = C[8];
  #pragma unroll
  for (int v = 0; v < NV; ++v) {
    float p00 = c_P[v][0][0], p01 = c_P[v][0][1], p02 = c_P[v][0][2];
    float p10 = c_P[v][1][0], p11 = c_P[v][1][1], p12 = c_P[v][1][2];
    float cx = m0 * p00 + m1 * p01 + m2 * p02;
    float cy = m0 * p10 + m1 * p11 + m2 * p12;
    float t0 = c0 * p00 + c1 * p01 + c2 * p02;
    float t1 = c3 * p00 + c4 * p01 + c5 * p02;
    float t2 = c6 * p00 + c7 * p01 + c8 * p02;
    float s2x = p00 * t0 + p01 * t1 + p02 * t2;
    t0 = c0 * p10 + c1 * p11 + c2 * p12;
    t1 = c3 * p10 + c4 * p11 + c5 * p12;
    t2 = c6 * p10 + c7 * p11 + c8 * p12;
    float s2y = p10 * t0 + p11 * t1 + p12 * t2;
    float lx = 0.5f * log2f(fmaxf(s2x, 1e-20f)) + 9.0f;
    float ly = 0.5f * log2f(fmaxf(s2y, 1e-20f)) + 9.0f;
    lx = fminf(fmaxf(lx, 0.0f), 7.0f);
    ly = fminf(fmaxf(ly, 0.0f), 7.0f);
    pl[(long)v * NS + n] = make_float4(cx, cy, lx, ly);
  }
}

// ---- interp: 4 threads/pair, 64B row loads, packed-fp16 accumulation ----
// lane q: pixel (q&1) of the (ix0, ix0+1) span, feature-half (q>>1).
// x-clamp folded into weights; all offsets pure shift arithmetic.
__global__ __launch_bounds__(256, 4) void interp5(const float4* __restrict__ pl,
                                                  const __half* __restrict__ pyr,
                                                  float* __restrict__ out)
{
  int bid = blockIdx.x;
  int swz = (bid & 7) * 5120 + (bid >> 3);    // 40960/8 = 5120 blocks per XCD
  int t = swz * 256 + threadIdx.x;
  int q = t & 3;
  int vlow = (t >> 2) & 1;
  int n = (t >> 3) & (NS - 1);
  int v2 = t >> 21;
  int v = v2 * 2 + vlow;

  float4 p = pl[(long)v * NS + n];
  float cx = p.x, cy = p.y, lx = p.z, ly = p.w;
  int l1f = (int)lx, l2f = (int)ly;
  float wx = lx - (float)l1f, wy = ly - (float)l2f;

  // u-side, hoisted per distinct l1 (s=0: floor, s=1: ceil)
  int ix0s[2], Arow[2], sh1[2];
  float wxls[2];
  float wl1s[2] = {1.0f - wx, wx};
  #pragma unroll
  for (int s = 0; s < 2; ++s) {
    int l1 = s ? min(l1f + 1, 7) : l1f;
    int Wl = 512 >> l1;
    float u = (cx * 0.5f + 0.5f) * (float)Wl - 0.5f;
    float uf = floorf(u);
    float fu = u - uf;
    int iu = (int)uf;
    bool edge = (iu < 0) || (iu >= Wl - 1);
    ix0s[s] = min(max(iu, 0), Wl - 1);
    wxls[s] = (q & 1) ? (edge ? 0.0f : fu) : (edge ? 1.0f : 1.0f - fu);
    sh1[s] = 9 - l1;
    Arow[s] = 1044480 - (1020 << (10 - l1));
  }
  // v-side, hoisted per distinct l2
  int iy0s[2], dys[2], Bv[2];
  float fvs[2];
  float wl2s[2] = {1.0f - wy, wy};
  #pragma unroll
  for (int s = 0; s < 2; ++s) {
    int l2 = s ? min(l2f + 1, 7) : l2f;
    int Hl = 512 >> l2;
    float vv = (cy * 0.5f + 0.5f) * (float)Hl - 0.5f;
    float vf = floorf(vv);
    fvs[s] = vv - vf;
    int iv = (int)vf;
    iy0s[s] = min(max(iv, 0), Hl - 1);
    int iy1 = min(max(iv + 1, 0), Hl - 1);
    dys[s] = iy1 - iy0s[s];
    Bv[s] = 1024 - (1024 >> l2);
  }

  // lane byte-slot inside a 64B row span: pixel (q&1), half (q>>1)
  const __half* bvq = pyr + (long)v * PYR_PX * FD + ((q & 1) * 16 + (q >> 1) * 8);

  int off0[4], off1[4];
  __half2 w0h[4], w1h[4];
  #pragma unroll
  for (int cb = 0; cb < 4; ++cb) {
    int i = cb >> 1, j = cb & 1;
    int o0 = Arow[i] + ((Bv[j] + iy0s[j]) << sh1[i]) + ix0s[i];
    off0[cb] = o0;
    off1[cb] = o0 + (dys[j] << sh1[i]);
    float wb = wl1s[i] * wl2s[j] * wxls[i];
    float w0 = wb * (1.0f - fvs[j]);
    float w1 = wb * fvs[j];
    w0h[cb] = __floats2half2_rn(w0, w0);
    w1h[cb] = __floats2half2_rn(w1, w1);
  }

  // batch-issue all 8 row loads
  uint4 d0[4], d1[4];
  #pragma unroll
  for (int cb = 0; cb < 4; ++cb) {
    d0[cb] = *(const uint4*)(bvq + (long)off0[cb] * FD);
    d1[cb] = *(const uint4*)(bvq + (long)off1[cb] * FD);
  }

  __half2 acc[4];
  #pragma unroll
  for (int w = 0; w < 4; ++w) acc[w] = __floats2half2_rn(0.f, 0.f);
  #pragma unroll
  for (int cb = 0; cb < 4; ++cb) {
    const __half2* h0 = (const __half2*)&d0[cb];
    const __half2* h1 = (const __half2*)&d1[cb];
    #pragma unroll
    for (int w = 0; w < 4; ++w) {
      acc[w] = __hfma2(h0[w], w0h[cb], acc[w]);
      acc[w] = __hfma2(h1[w], w1h[cb], acc[w]);
    }
  }

  // combine the two pixels of the bilinear x-span (lanes q and q^1)
  #pragma unroll
  for (int w = 0; w < 4; ++w) {
    int a = *(int*)&acc[w];
    int b = __shfl_xor(a, 1);
    acc[w] = __hadd2(acc[w], *(__half2*)&b);
  }

  __half2 s0 = (q & 1) ? acc[2] : acc[0];
  __half2 s1 = (q & 1) ? acc[3] : acc[1];
  float2 f0 = __half22float2(s0);
  float2 f1 = __half22float2(s1);
  *(float4*)(out + ((long)n * NV + v) * FD + q * 4) =
      make_float4(f0.x, f0.y, f1.x, f1.y);
}

extern "C" void kernel_launch(void* const* d_in, const int* in_sizes, int n_in,
                              void* d_out, int out_size, void* d_ws, size_t ws_size,
                              hipStream_t stream)
{
  const float* means = (const float*)d_in[0];
  const float* covs  = (const float*)d_in[1];
  const float* fm    = (const float*)d_in[2];
  float* out = (float*)d_out;
  __half* pyr = (__half*)d_ws;
  float4* pl  = (float4*)((char*)d_ws + PYR_BYTES);

  build_w<<<NV * 512, 256, 0, stream>>>(fm, pyr);
  {
    int tA = NV * 64 * 2040;   // levels 1..3 from 0
    pool_hN<0, 3><<<(tA + 255) / 256, 256, 0, stream>>>(pyr);
    int tB = NV * 8 * 2040;    // levels 4..6 from 3
    pool_hN<3, 3><<<(tB + 255) / 256, 256, 0, stream>>>(pyr);
    int tC = NV * 4 * 2040;    // level 7 from 6
    pool_hN<6, 1><<<(tC + 255) / 256, 256, 0, stream>>>(pyr);
  }
  proj_kernel<<<(NS + 255) / 256, 256, 0, stream>>>(means, covs, pl);

  interp5<<<40960, 256, 0, stream>>>(pl, pyr, out);
}

// Round 9
// 297.198 us; speedup vs baseline: 1.0635x; 1.0635x over previous
//
#include <hip/hip_runtime.h>
#include <hip/hip_fp16.h>

// RipEncoding, round 9: interp rewritten array-free (defeats PromoteAlloca->LDS),
// load batch pinned with sched_barrier(0). Build side unchanged from round 8.
//
// ws layout: [0, 332928000) fp16 pyramid (10 verts x 1020x1020 px x 16 halfs)
//            [332928000, +41943040) float4 proj table [v][n] = (cx,cy,lx,ly)

#define NV 10
#define FD 16
#define NS 262144          // 2^18
#define PYR_PX 1040400L    // 1020*1020 pixels per vertex
#define PYR_BYTES 332928000L

__constant__ float c_P[NV][2][3] = {
  {{-0.7071067811865476f, 0.7071067811865476f, 0.0f},
   {-0.4082482904638631f,-0.4082482904638631f, 0.8164965809277261f}},
  {{-0.7071067811865476f, 0.7071067811865476f, 0.0f},
   { 0.4082482904638631f, 0.4082482904638631f, 0.8164965809277261f}},
  {{ 0.7071067811865476f, 0.7071067811865476f, 0.0f},
   {-0.4082482904638631f, 0.4082482904638631f, 0.8164965809277261f}},
  {{ 0.7071067811865476f, 0.7071067811865476f, 0.0f},
   { 0.4082482904638631f,-0.4082482904638631f, 0.8164965809277261f}},
  {{-1.0f, 0.0f, 0.0f},
   { 0.0f,-0.3568220897730899f, 0.9341723589627157f}},
  {{-1.0f, 0.0f, 0.0f},
   { 0.0f, 0.3568220897730899f, 0.9341723589627157f}},
  {{ 0.0f, 1.0f, 0.0f},
   {-0.9341723589627157f, 0.0f, 0.3568220897730899f}},
  {{ 0.0f, 1.0f, 0.0f},
   { 0.9341723589627157f, 0.0f, 0.3568220897730899f}},
  {{-0.3568220897730899f, 0.9341723589627157f, 0.0f},
   { 0.0f, 0.0f, 1.0f}},
  {{ 0.3568220897730899f, 0.9341723589627157f, 0.0f},
   { 0.0f, 0.0f, 1.0f}},
};

__constant__ int c_CW[8] = {0, 512, 768, 896, 960, 992, 1008, 1016};

// arithmetic plane offset: CW[l] = 1024 - (1024>>l)
// offp(l1,l2) = 1020*CW[l1] + (512>>l1)*CW[l2]
__device__ __forceinline__ int offp_a(int l1, int l2) {
  return 1044480 - (1020 << (10 - l1)) + ((1024 - (1024 >> l2)) << (9 - l1));
}
__device__ __forceinline__ long offp(int l1, int l2) {
  return 1020L * (long)c_CW[l1] + (long)(512 >> l1) * (long)c_CW[l2];
}

__device__ __forceinline__ uint2 pack4(float4 f) {
  __half2 h0 = __floats2half2_rn(f.x, f.y);
  __half2 h1 = __floats2half2_rn(f.z, f.w);
  uint2 s;
  s.x = *(unsigned int*)&h0;
  s.y = *(unsigned int*)&h1;
  return s;
}

// ---- pass 1: one block per (v, y) row; all 8 width levels from LDS ----
__global__ __launch_bounds__(256) void build_w(const float* __restrict__ fm,
                                               __half* __restrict__ pyr)
{
  __shared__ float4 lds[512 * 5];   // pixel p, quad fb at lds[p*5+fb]; 40 KB
  int b = blockIdx.x;
  int v = b >> 9, y = b & 511;
  int t = threadIdx.x;
  const float4* src = (const float4*)(fm + ((long)v * 262144L + (long)y * 512) * FD);
  #pragma unroll
  for (int i = 0; i < 8; ++i) {
    int u = t + 256 * i;                        // linear float4 index 0..2047
    float4 d = src[u];
    lds[(u >> 2) * 5 + (u & 3)] = d;
  }
  __syncthreads();
  __half* bv = pyr + (long)v * PYR_PX * FD;
  {                                             // level (0,0): convert row
    uint2* dst = (uint2*)(bv + (long)y * 512 * FD);
    #pragma unroll
    for (int i = 0; i < 8; ++i) {
      int u = t + 256 * i;
      dst[u] = pack4(lds[(u >> 2) * 5 + (u & 3)]);
    }
  }
  #pragma unroll
  for (int l1 = 1; l1 <= 7; ++l1) {
    int W = 512 >> l1;
    int units = W * 4;
    float4 r[4];
    #pragma unroll
    for (int i = 0; i < 4; ++i) {
      int u = t + 256 * i;
      if (u < units) {
        int px = u >> 2, fb = u & 3;
        float4 a = lds[(2 * px) * 5 + fb];
        float4 c = lds[(2 * px + 1) * 5 + fb];
        r[i].x = 0.5f * (a.x + c.x); r[i].y = 0.5f * (a.y + c.y);
        r[i].z = 0.5f * (a.z + c.z); r[i].w = 0.5f * (a.w + c.w);
      }
    }
    __syncthreads();
    uint2* dst = (uint2*)(bv + (offp(l1, 0) + (long)y * W) * FD);
    #pragma unroll
    for (int i = 0; i < 4; ++i) {
      int u = t + 256 * i;
      if (u < units) {
        int px = u >> 2, fb = u & 3;
        lds[px * 5 + fb] = r[i];
        dst[u] = pack4(r[i]);
      }
    }
    __syncthreads();
  }
}

// ---- pass 2: fused height pools (3 launches) ----
template<int L2SRC, int NLEV>
__global__ __launch_bounds__(256) void pool_hN(__half* __restrict__ pyr)
{
  constexpr int R = 1 << NLEV;
  constexpr int HL = 512 >> (L2SRC + NLEV);     // rows of the last level
  int total = NV * HL * 2040;
  int t = blockIdx.x * 256 + threadIdx.x;
  if (t >= total) return;
  int u = t % 2040;
  int r2 = t / 2040;
  int c = u >> 1, k = u & 1;          // virtual column, 16B slot
  int y = r2 % HL;
  int v = r2 / HL;
  int l1 = 0;
  #pragma unroll
  for (int i = 1; i < 8; ++i) l1 += (c >= c_CW[i]) ? 1 : 0;
  int x = c - c_CW[l1];
  int W = 512 >> l1;
  __half* bv = pyr + (long)v * PYR_PX * FD;
  const __half* src = bv + (long)offp_a(l1, L2SRC) * FD;

  uint4 d[R];
  long base = ((long)(y * R) * W + x) * FD + k * 8;
  #pragma unroll
  for (int r = 0; r < R; ++r)
    d[r] = *(const uint4*)(src + base + (long)r * W * FD);

  const __half2 hhalf = __floats2half2_rn(0.5f, 0.5f);
  #pragma unroll
  for (int lev = 1; lev <= NLEV; ++lev) {
    int cnt = R >> lev;
    __half* dst = bv + (long)offp_a(l1, L2SRC + lev) * FD;
    #pragma unroll
    for (int r = 0; r < cnt; ++r) {
      const __half2* a = (const __half2*)&d[2 * r];
      const __half2* b = (const __half2*)&d[2 * r + 1];
      uint4 res;
      __half2* rr = (__half2*)&res;
      #pragma unroll
      for (int j = 0; j < 4; ++j)
        rr[j] = __hmul2(__hadd2(a[j], b[j]), hhalf);
      d[r] = res;
      *(uint4*)(dst + (((long)(y * cnt + r)) * W + x) * FD + k * 8) = res;
    }
  }
}

// ---- projection/level precompute: one thread per sample ----
__global__ __launch_bounds__(256) void proj_kernel(const float* __restrict__ means,
                                                   const float* __restrict__ covs,
                                                   float4* __restrict__ pl)
{
  int n = blockIdx.x * 256 + threadIdx.x;
  if (n >= NS) return;
  float m0 = means[3 * n], m1 = means[3 * n + 1], m2 = means[3 * n + 2];
  const float* C = covs + 9L * n;
  float c0 = C[0], c1 = C[1], c2 = C[2];
  float c3 = C[3], c4 = C[4], c5 = C[5];
  float c6 = C[6], c7 = C[7], c8 = C[8];
  #pragma unroll
  for (int v = 0; v < NV; ++v) {
    float p00 = c_P[v][0][0], p01 = c_P[v][0][1], p02 = c_P[v][0][2];
    float p10 = c_P[v][1][0], p11 = c_P[v][1][1], p12 = c_P[v][1][2];
    float cx = m0 * p00 + m1 * p01 + m2 * p02;
    float cy = m0 * p10 + m1 * p11 + m2 * p12;
    float t0 = c0 * p00 + c1 * p01 + c2 * p02;
    float t1 = c3 * p00 + c4 * p01 + c5 * p02;
    float t2 = c6 * p00 + c7 * p01 + c8 * p02;
    float s2x = p00 * t0 + p01 * t1 + p02 * t2;
    t0 = c0 * p10 + c1 * p11 + c2 * p12;
    t1 = c3 * p10 + c4 * p11 + c5 * p12;
    t2 = c6 * p10 + c7 * p11 + c8 * p12;
    float s2y = p10 * t0 + p11 * t1 + p12 * t2;
    float lx = 0.5f * log2f(fmaxf(s2x, 1e-20f)) + 9.0f;
    float ly = 0.5f * log2f(fmaxf(s2y, 1e-20f)) + 9.0f;
    lx = fminf(fmaxf(lx, 0.0f), 7.0f);
    ly = fminf(fmaxf(ly, 0.0f), 7.0f);
    pl[(long)v * NS + n] = make_float4(cx, cy, lx, ly);
  }
}

// ---- interp: 4 threads/pair, 64B row loads, array-free, pinned batch ----
__global__ __launch_bounds__(256) void interp6(const float4* __restrict__ pl,
                                               const __half* __restrict__ pyr,
                                               float* __restrict__ out)
{
  int bid = blockIdx.x;
  int swz = (bid & 7) * 5120 + (bid >> 3);    // 40960/8 = 5120 blocks per XCD
  int t = swz * 256 + threadIdx.x;
  int q = t & 3;
  int vlow = (t >> 2) & 1;
  int n = (t >> 3) & (NS - 1);
  int v2 = t >> 21;
  int v = v2 * 2 + vlow;

  float4 p = pl[(long)v * NS + n];
  float cx = p.x, cy = p.y, lx = p.z, ly = p.w;
  int l1f = (int)lx, l2f = (int)ly;
  float wx = lx - (float)l1f, wy = ly - (float)l2f;
  int l1c = min(l1f + 1, 7);
  int l2c = min(l2f + 1, 7);

  bool qodd = (q & 1);

  // ---- u-side, scalar per distinct l1 ----
  // s = 0 (floor level)
  int sh_0 = 9 - l1f;
  int Ar_0 = 1044480 - (1020 << (10 - l1f));
  float u0 = (cx * 0.5f + 0.5f) * (float)(1 << sh_0) - 0.5f;
  float uf0 = floorf(u0);
  float fu0 = u0 - uf0;
  int iu0 = (int)uf0;
  bool e0 = (iu0 < 0) || (iu0 >= (1 << sh_0) - 1);
  int ix_0 = min(max(iu0, 0), (1 << sh_0) - 1);
  float wxl_0 = qodd ? (e0 ? 0.0f : fu0) : (e0 ? 1.0f : 1.0f - fu0);
  // s = 1 (ceil level)
  int sh_1 = 9 - l1c;
  int Ar_1 = 1044480 - (1020 << (10 - l1c));
  float u1 = (cx * 0.5f + 0.5f) * (float)(1 << sh_1) - 0.5f;
  float uf1 = floorf(u1);
  float fu1 = u1 - uf1;
  int iu1 = (int)uf1;
  bool e1 = (iu1 < 0) || (iu1 >= (1 << sh_1) - 1);
  int ix_1 = min(max(iu1, 0), (1 << sh_1) - 1);
  float wxl_1 = qodd ? (e1 ? 0.0f : fu1) : (e1 ? 1.0f : 1.0f - fu1);

  float wl1_0 = 1.0f - wx, wl1_1 = wx;

  // ---- v-side, scalar per distinct l2 ----
  int H0 = 512 >> l2f;
  float vv0 = (cy * 0.5f + 0.5f) * (float)H0 - 0.5f;
  float vf0 = floorf(vv0);
  float fv_0 = vv0 - vf0;
  int iv0 = (int)vf0;
  int iy_0 = min(max(iv0, 0), H0 - 1);
  int dy_0 = min(max(iv0 + 1, 0), H0 - 1) - iy_0;
  int Bv_0 = 1024 - (1024 >> l2f);

  int H1 = 512 >> l2c;
  float vv1 = (cy * 0.5f + 0.5f) * (float)H1 - 0.5f;
  float vf1 = floorf(vv1);
  float fv_1 = vv1 - vf1;
  int iv1 = (int)vf1;
  int iy_1 = min(max(iv1, 0), H1 - 1);
  int dy_1 = min(max(iv1 + 1, 0), H1 - 1) - iy_1;
  int Bv_1 = 1024 - (1024 >> l2c);

  float wl2_0 = 1.0f - wy, wl2_1 = wy;

  // ---- combo offsets (pixel units) and weights, all named scalars ----
  int oA = Ar_0 + ((Bv_0 + iy_0) << sh_0) + ix_0;    // (l1f, l2f) row iy0
  int oB = oA + (dy_0 << sh_0);                      // row iy1
  int oC = Ar_0 + ((Bv_1 + iy_1) << sh_0) + ix_0;    // (l1f, l2c)
  int oD = oC + (dy_1 << sh_0);
  int oE = Ar_1 + ((Bv_0 + iy_0) << sh_1) + ix_1;    // (l1c, l2f)
  int oF = oE + (dy_0 << sh_1);
  int oG = Ar_1 + ((Bv_1 + iy_1) << sh_1) + ix_1;    // (l1c, l2c)
  int oH = oG + (dy_1 << sh_1);

  float wb00 = wl1_0 * wl2_0 * wxl_0;
  float wb01 = wl1_0 * wl2_1 * wxl_0;
  float wb10 = wl1_1 * wl2_0 * wxl_1;
  float wb11 = wl1_1 * wl2_1 * wxl_1;
  __half2 wA = __float2half2_rn(wb00 * (1.0f - fv_0));
  __half2 wB = __float2half2_rn(wb00 * fv_0);
  __half2 wC = __float2half2_rn(wb01 * (1.0f - fv_1));
  __half2 wD = __float2half2_rn(wb01 * fv_1);
  __half2 wE = __float2half2_rn(wb10 * (1.0f - fv_0));
  __half2 wF = __float2half2_rn(wb10 * fv_0);
  __half2 wG = __float2half2_rn(wb11 * (1.0f - fv_1));
  __half2 wH = __float2half2_rn(wb11 * fv_1);

  // lane byte-slot inside a 64B row span: pixel (q&1), half (q>>1)
  const __half* bvq = pyr + (long)v * PYR_PX * FD + ((q & 1) * 16 + (q >> 1) * 8);

  // ---- batch-issue all 8 row loads; pin with sched_barrier ----
  uint4 dA = *(const uint4*)(bvq + (long)oA * FD);
  uint4 dB = *(const uint4*)(bvq + (long)oB * FD);
  uint4 dC = *(const uint4*)(bvq + (long)oC * FD);
  uint4 dD = *(const uint4*)(bvq + (long)oD * FD);
  uint4 dE = *(const uint4*)(bvq + (long)oE * FD);
  uint4 dF = *(const uint4*)(bvq + (long)oF * FD);
  uint4 dG = *(const uint4*)(bvq + (long)oG * FD);
  uint4 dH = *(const uint4*)(bvq + (long)oH * FD);
  __builtin_amdgcn_sched_barrier(0);

  __half2 z = __float2half2_rn(0.0f);
  __half2 acc0 = z, acc1 = z, acc2 = z, acc3 = z;
  #define ACC8(D, W) { const __half2* hh = (const __half2*)&(D);      \
    acc0 = __hfma2(hh[0], (W), acc0); acc1 = __hfma2(hh[1], (W), acc1); \
    acc2 = __hfma2(hh[2], (W), acc2); acc3 = __hfma2(hh[3], (W), acc3); }
  ACC8(dA, wA) ACC8(dB, wB) ACC8(dC, wC) ACC8(dD, wD)
  ACC8(dE, wE) ACC8(dF, wF) ACC8(dG, wG) ACC8(dH, wH)
  #undef ACC8

  // combine the two pixels of the bilinear x-span (lanes q and q^1)
  int a0 = *(int*)&acc0, a1 = *(int*)&acc1;
  int a2 = *(int*)&acc2, a3 = *(int*)&acc3;
  int b0 = __shfl_xor(a0, 1), b1 = __shfl_xor(a1, 1);
  int b2 = __shfl_xor(a2, 1), b3 = __shfl_xor(a3, 1);
  acc0 = __hadd2(acc0, *(__half2*)&b0);
  acc1 = __hadd2(acc1, *(__half2*)&b1);
  acc2 = __hadd2(acc2, *(__half2*)&b2);
  acc3 = __hadd2(acc3, *(__half2*)&b3);

  __half2 s0 = qodd ? acc2 : acc0;
  __half2 s1 = qodd ? acc3 : acc1;
  float2 f0 = __half22float2(s0);
  float2 f1 = __half22float2(s1);
  *(float4*)(out + ((long)n * NV + v) * FD + q * 4) =
      make_float4(f0.x, f0.y, f1.x, f1.y);
}

extern "C" void kernel_launch(void* const* d_in, const int* in_sizes, int n_in,
                              void* d_out, int out_size, void* d_ws, size_t ws_size,
                              hipStream_t stream)
{
  const float* means = (const float*)d_in[0];
  const float* covs  = (const float*)d_in[1];
  const float* fm    = (const float*)d_in[2];
  float* out = (float*)d_out;
  __half* pyr = (__half*)d_ws;
  float4* pl  = (float4*)((char*)d_ws + PYR_BYTES);

  build_w<<<NV * 512, 256, 0, stream>>>(fm, pyr);
  {
    int tA = NV * 64 * 2040;   // levels 1..3 from 0
    pool_hN<0, 3><<<(tA + 255) / 256, 256, 0, stream>>>(pyr);
    int tB = NV * 8 * 2040;    // levels 4..6 from 3
    pool_hN<3, 3><<<(tB + 255) / 256, 256, 0, stream>>>(pyr);
    int tC = NV * 4 * 2040;    // level 7 from 6
    pool_hN<6, 1><<<(tC + 255) / 256, 256, 0, stream>>>(pyr);
  }
  proj_kernel<<<(NS + 255) / 256, 256, 0, stream>>>(means, covs, pl);

  interp6<<<40960, 256, 0, stream>>>(pl, pyr, out);
}

// Round 10
// 273.640 us; speedup vs baseline: 1.1550x; 1.0861x over previous
//
#include <hip/hip_runtime.h>
#include <hip/hip_fp16.h>

// RipEncoding, round 10: fused single-pass pyramid build (width levels +
// height levels 1..3 in one kernel, LDS-staged), pool tail for levels 4..7,
// round-9 interp unchanged.
//
// ws layout: [0, 332928000) fp16 pyramid (10 verts x 1020x1020 px x 16 halfs)
//            [332928000, +41943040) float4 proj table [v][n] = (cx,cy,lx,ly)

#define NV 10
#define FD 16
#define NS 262144          // 2^18
#define PYR_PX 1040400L    // 1020*1020 pixels per vertex
#define PYR_BYTES 332928000L

__constant__ float c_P[NV][2][3] = {
  {{-0.7071067811865476f, 0.7071067811865476f, 0.0f},
   {-0.4082482904638631f,-0.4082482904638631f, 0.8164965809277261f}},
  {{-0.7071067811865476f, 0.7071067811865476f, 0.0f},
   { 0.4082482904638631f, 0.4082482904638631f, 0.8164965809277261f}},
  {{ 0.7071067811865476f, 0.7071067811865476f, 0.0f},
   {-0.4082482904638631f, 0.4082482904638631f, 0.8164965809277261f}},
  {{ 0.7071067811865476f, 0.7071067811865476f, 0.0f},
   { 0.4082482904638631f,-0.4082482904638631f, 0.8164965809277261f}},
  {{-1.0f, 0.0f, 0.0f},
   { 0.0f,-0.3568220897730899f, 0.9341723589627157f}},
  {{-1.0f, 0.0f, 0.0f},
   { 0.0f, 0.3568220897730899f, 0.9341723589627157f}},
  {{ 0.0f, 1.0f, 0.0f},
   {-0.9341723589627157f, 0.0f, 0.3568220897730899f}},
  {{ 0.0f, 1.0f, 0.0f},
   { 0.9341723589627157f, 0.0f, 0.3568220897730899f}},
  {{-0.3568220897730899f, 0.9341723589627157f, 0.0f},
   { 0.0f, 0.0f, 1.0f}},
  {{ 0.3568220897730899f, 0.9341723589627157f, 0.0f},
   { 0.0f, 0.0f, 1.0f}},
};

__constant__ int c_CW[8] = {0, 512, 768, 896, 960, 992, 1008, 1016};

// arithmetic plane offset: CW[l] = 1024 - (1024>>l)
// offp(l1,l2) = 1020*CW[l1] + (512>>l1)*CW[l2]
__device__ __forceinline__ int offp_a(int l1, int l2) {
  return 1044480 - (1020 << (10 - l1)) + ((1024 - (1024 >> l2)) << (9 - l1));
}

__device__ __forceinline__ uint4 havg(uint4 a, uint4 c, __half2 hhalf) {
  uint4 res;
  __half2* rr = (__half2*)&res;
  const __half2* ha = (const __half2*)&a;
  const __half2* hc = (const __half2*)&c;
  #pragma unroll
  for (int j = 0; j < 4; ++j) rr[j] = __hmul2(__hadd2(ha[j], hc[j]), hhalf);
  return res;
}

// ---- fused build: one block per (v, 8-row band, 128-px strip) ----
// Produces all width levels (l1,0) and height levels (l1,1..3) for its tile.
__global__ __launch_bounds__(256) void build_all(const float* __restrict__ fm,
                                                 __half* __restrict__ pyr)
{
  __shared__ uint4 ldsA[2048];   // 32 KB: tiles for even l1 (0,2,4,6)
  __shared__ uint4 ldsB[1024];   // 16 KB: tiles for odd l1 (1,3,5,7)
  int bid = blockIdx.x;
  int v = bid >> 8;              // 256 blocks per vertex
  int rem = bid & 255;
  int b = rem >> 2;              // band: rows [8b, 8b+8) of full-height planes
  int s = rem & 3;               // x-strip: fm px [128s, 128s+128)
  int t = threadIdx.x;

  __half* bv = pyr + (long)v * PYR_PX * FD;
  uint4* bv4 = (uint4*)bv;       // 2 uint4 per pixel
  const __half2 hhalf = __floats2half2_rn(0.5f, 0.5f);

  // phase 0: load 8x128 f32 strip, convert, write (0,0), stage LDS A
  {
    const float4* src = (const float4*)(fm +
        (((long)v * 512 + b * 8) * 512 + s * 128) * FD);
    uint2* ldsu2 = (uint2*)ldsA;
    uint2* g0 = (uint2*)bv;      // plane (0,0) at pixel offset 0
    #pragma unroll
    for (int i = 0; i < 16; ++i) {
      int u = t + 256 * i;           // 4096 float4 units
      int r = u >> 9;                // 512 float4 per strip-row
      int f4 = u & 511;
      int px = f4 >> 2, q = f4 & 3;
      float4 d = src[(long)r * 2048 + f4];   // fm row stride = 2048 float4
      __half2 h0 = __floats2half2_rn(d.x, d.y);
      __half2 h1 = __floats2half2_rn(d.z, d.w);
      uint2 val;
      val.x = *(unsigned*)&h0; val.y = *(unsigned*)&h1;
      ldsu2[(r * 128 + px) * 4 + q] = val;
      g0[((long)(b * 8 + r) * 512 + s * 128 + px) * 4 + q] = val;
    }
  }
  __syncthreads();

  #pragma unroll
  for (int l1 = 0; l1 < 8; ++l1) {
    uint4* cur = (l1 & 1) ? ldsB : ldsA;
    const int Wc = 128 >> l1;          // strip-local width at l1

    // width-pool l1 -> l1+1 (LDS + global (l1+1, 0))
    if (l1 < 7) {
      uint4* nxt = (l1 & 1) ? ldsA : ldsB;
      const int Wn = Wc >> 1;
      const int units = 8 * Wn * 2;
      const int Wgn = 512 >> (l1 + 1);
      const int colbase = offp_a(l1 + 1, 0) + s * Wn;
      for (int u = t; u < units; u += 256) {
        int k = u & 1;
        int xr = u >> 1;
        int x = xr & (Wn - 1);
        int r = xr >> (6 - l1);        // xr / Wn, Wn = 64>>l1
        uint4 a = cur[(r * Wc + 2 * x) * 2 + k];
        uint4 c = cur[(r * Wc + 2 * x + 1) * 2 + k];
        uint4 res = havg(a, c, hhalf);
        nxt[(r * Wn + x) * 2 + k] = res;
        bv4[(long)(colbase + (b * 8 + r) * Wgn + x) * 2 + k] = res;
      }
    }

    // height-pool cur tile -> global (l1, 1..3)
    {
      const int slots = Wc * 2;
      if (t < slots) {
        int k = t & 1, x = t >> 1;
        const int Wg = 512 >> l1;
        uint4 r0 = cur[(0 * Wc + x) * 2 + k];
        uint4 r1 = cur[(1 * Wc + x) * 2 + k];
        uint4 r2 = cur[(2 * Wc + x) * 2 + k];
        uint4 r3 = cur[(3 * Wc + x) * 2 + k];
        uint4 r4 = cur[(4 * Wc + x) * 2 + k];
        uint4 r5 = cur[(5 * Wc + x) * 2 + k];
        uint4 r6 = cur[(6 * Wc + x) * 2 + k];
        uint4 r7 = cur[(7 * Wc + x) * 2 + k];
        uint4 a0 = havg(r0, r1, hhalf), a1 = havg(r2, r3, hhalf);
        uint4 a2 = havg(r4, r5, hhalf), a3 = havg(r6, r7, hhalf);
        uint4 b0 = havg(a0, a1, hhalf), b1 = havg(a2, a3, hhalf);
        uint4 c0 = havg(b0, b1, hhalf);
        int gx = s * Wc + x;
        long p1 = (long)offp_a(l1, 1) + (long)(b * 4) * Wg + gx;
        bv4[p1 * 2 + k] = a0;
        bv4[(p1 + Wg) * 2 + k] = a1;
        bv4[(p1 + 2 * Wg) * 2 + k] = a2;
        bv4[(p1 + 3 * Wg) * 2 + k] = a3;
        long p2 = (long)offp_a(l1, 2) + (long)(b * 2) * Wg + gx;
        bv4[p2 * 2 + k] = b0;
        bv4[(p2 + Wg) * 2 + k] = b1;
        long p3 = (long)offp_a(l1, 3) + (long)b * Wg + gx;
        bv4[p3 * 2 + k] = c0;
      }
    }
    __syncthreads();
  }
}

// ---- pool tail: levels (l1, L2SRC+1..L2SRC+NLEV) from (l1, L2SRC) ----
template<int L2SRC, int NLEV>
__global__ __launch_bounds__(256) void pool_hN(__half* __restrict__ pyr)
{
  constexpr int R = 1 << NLEV;
  constexpr int HL = 512 >> (L2SRC + NLEV);     // rows of the last level
  int total = NV * HL * 2040;
  int t = blockIdx.x * 256 + threadIdx.x;
  if (t >= total) return;
  int u = t % 2040;
  int r2 = t / 2040;
  int c = u >> 1, k = u & 1;          // virtual column, 16B slot
  int y = r2 % HL;
  int v = r2 / HL;
  int l1 = 0;
  #pragma unroll
  for (int i = 1; i < 8; ++i) l1 += (c >= c_CW[i]) ? 1 : 0;
  int x = c - c_CW[l1];
  int W = 512 >> l1;
  __half* bv = pyr + (long)v * PYR_PX * FD;
  const __half* src = bv + (long)offp_a(l1, L2SRC) * FD;

  uint4 d[R];
  long base = ((long)(y * R) * W + x) * FD + k * 8;
  #pragma unroll
  for (int r = 0; r < R; ++r)
    d[r] = *(const uint4*)(src + base + (long)r * W * FD);

  const __half2 hhalf = __floats2half2_rn(0.5f, 0.5f);
  #pragma unroll
  for (int lev = 1; lev <= NLEV; ++lev) {
    int cnt = R >> lev;
    __half* dst = bv + (long)offp_a(l1, L2SRC + lev) * FD;
    #pragma unroll
    for (int r = 0; r < cnt; ++r) {
      d[r] = havg(d[2 * r], d[2 * r + 1], hhalf);
      *(uint4*)(dst + (((long)(y * cnt + r)) * W + x) * FD + k * 8) = d[r];
    }
  }
}

// ---- projection/level precompute: one thread per sample ----
__global__ __launch_bounds__(256) void proj_kernel(const float* __restrict__ means,
                                                   const float* __restrict__ covs,
                                                   float4* __restrict__ pl)
{
  int n = blockIdx.x * 256 + threadIdx.x;
  if (n >= NS) return;
  float m0 = means[3 * n], m1 = means[3 * n + 1], m2 = means[3 * n + 2];
  const float* C = covs + 9L * n;
  float c0 = C[0], c1 = C[1], c2 = C[2];
  float c3 = C[3], c4 = C[4], c5 = C[5];
  float c6 = C[6], c7 = C[7], c8 = C[8];
  #pragma unroll
  for (int v = 0; v < NV; ++v) {
    float p00 = c_P[v][0][0], p01 = c_P[v][0][1], p02 = c_P[v][0][2];
    float p10 = c_P[v][1][0], p11 = c_P[v][1][1], p12 = c_P[v][1][2];
    float cx = m0 * p00 + m1 * p01 + m2 * p02;
    float cy = m0 * p10 + m1 * p11 + m2 * p12;
    float t0 = c0 * p00 + c1 * p01 + c2 * p02;
    float t1 = c3 * p00 + c4 * p01 + c5 * p02;
    float t2 = c6 * p00 + c7 * p01 + c8 * p02;
    float s2x = p00 * t0 + p01 * t1 + p02 * t2;
    t0 = c0 * p10 + c1 * p11 + c2 * p12;
    t1 = c3 * p10 + c4 * p11 + c5 * p12;
    t2 = c6 * p10 + c7 * p11 + c8 * p12;
    float s2y = p10 * t0 + p11 * t1 + p12 * t2;
    float lx = 0.5f * log2f(fmaxf(s2x, 1e-20f)) + 9.0f;
    float ly = 0.5f * log2f(fmaxf(s2y, 1e-20f)) + 9.0f;
    lx = fminf(fmaxf(lx, 0.0f), 7.0f);
    ly = fminf(fmaxf(ly, 0.0f), 7.0f);
    pl[(long)v * NS + n] = make_float4(cx, cy, lx, ly);
  }
}

// ---- interp: 4 threads/pair, 64B row loads, array-free, pinned batch ----
__global__ __launch_bounds__(256) void interp6(const float4* __restrict__ pl,
                                               const __half* __restrict__ pyr,
                                               float* __restrict__ out)
{
  int bid = blockIdx.x;
  int swz = (bid & 7) * 5120 + (bid >> 3);    // 40960/8 = 5120 blocks per XCD
  int t = swz * 256 + threadIdx.x;
  int q = t & 3;
  int vlow = (t >> 2) & 1;
  int n = (t >> 3) & (NS - 1);
  int v2 = t >> 21;
  int v = v2 * 2 + vlow;

  float4 p = pl[(long)v * NS + n];
  float cx = p.x, cy = p.y, lx = p.z, ly = p.w;
  int l1f = (int)lx, l2f = (int)ly;
  float wx = lx - (float)l1f, wy = ly - (float)l2f;
  int l1c = min(l1f + 1, 7);
  int l2c = min(l2f + 1, 7);

  bool qodd = (q & 1);

  // ---- u-side, scalar per distinct l1 ----
  int sh_0 = 9 - l1f;
  int Ar_0 = 1044480 - (1020 << (10 - l1f));
  float u0 = (cx * 0.5f + 0.5f) * (float)(1 << sh_0) - 0.5f;
  float uf0 = floorf(u0);
  float fu0 = u0 - uf0;
  int iu0 = (int)uf0;
  bool e0 = (iu0 < 0) || (iu0 >= (1 << sh_0) - 1);
  int ix_0 = min(max(iu0, 0), (1 << sh_0) - 1);
  float wxl_0 = qodd ? (e0 ? 0.0f : fu0) : (e0 ? 1.0f : 1.0f - fu0);
  int sh_1 = 9 - l1c;
  int Ar_1 = 1044480 - (1020 << (10 - l1c));
  float u1 = (cx * 0.5f + 0.5f) * (float)(1 << sh_1) - 0.5f;
  float uf1 = floorf(u1);
  float fu1 = u1 - uf1;
  int iu1 = (int)uf1;
  bool e1 = (iu1 < 0) || (iu1 >= (1 << sh_1) - 1);
  int ix_1 = min(max(iu1, 0), (1 << sh_1) - 1);
  float wxl_1 = qodd ? (e1 ? 0.0f : fu1) : (e1 ? 1.0f : 1.0f - fu1);

  float wl1_0 = 1.0f - wx, wl1_1 = wx;

  // ---- v-side, scalar per distinct l2 ----
  int H0 = 512 >> l2f;
  float vv0 = (cy * 0.5f + 0.5f) * (float)H0 - 0.5f;
  float vf0 = floorf(vv0);
  float fv_0 = vv0 - vf0;
  int iv0 = (int)vf0;
  int iy_0 = min(max(iv0, 0), H0 - 1);
  int dy_0 = min(max(iv0 + 1, 0), H0 - 1) - iy_0;
  int Bv_0 = 1024 - (1024 >> l2f);

  int H1 = 512 >> l2c;
  float vv1 = (cy * 0.5f + 0.5f) * (float)H1 - 0.5f;
  float vf1 = floorf(vv1);
  float fv_1 = vv1 - vf1;
  int iv1 = (int)vf1;
  int iy_1 = min(max(iv1, 0), H1 - 1);
  int dy_1 = min(max(iv1 + 1, 0), H1 - 1) - iy_1;
  int Bv_1 = 1024 - (1024 >> l2c);

  float wl2_0 = 1.0f - wy, wl2_1 = wy;

  // ---- combo offsets (pixel units) and weights, all named scalars ----
  int oA = Ar_0 + ((Bv_0 + iy_0) << sh_0) + ix_0;    // (l1f, l2f) row iy0
  int oB = oA + (dy_0 << sh_0);                      // row iy1
  int oC = Ar_0 + ((Bv_1 + iy_1) << sh_0) + ix_0;    // (l1f, l2c)
  int oD = oC + (dy_1 << sh_0);
  int oE = Ar_1 + ((Bv_0 + iy_0) << sh_1) + ix_1;    // (l1c, l2f)
  int oF = oE + (dy_0 << sh_1);
  int oG = Ar_1 + ((Bv_1 + iy_1) << sh_1) + ix_1;    // (l1c, l2c)
  int oH = oG + (dy_1 << sh_1);

  float wb00 = wl1_0 * wl2_0 * wxl_0;
  float wb01 = wl1_0 * wl2_1 * wxl_0;
  float wb10 = wl1_1 * wl2_0 * wxl_1;
  float wb11 = wl1_1 * wl2_1 * wxl_1;
  __half2 wA = __float2half2_rn(wb00 * (1.0f - fv_0));
  __half2 wB = __float2half2_rn(wb00 * fv_0);
  __half2 wC = __float2half2_rn(wb01 * (1.0f - fv_1));
  __half2 wD = __float2half2_rn(wb01 * fv_1);
  __half2 wE = __float2half2_rn(wb10 * (1.0f - fv_0));
  __half2 wF = __float2half2_rn(wb10 * fv_0);
  __half2 wG = __float2half2_rn(wb11 * (1.0f - fv_1));
  __half2 wH = __float2half2_rn(wb11 * fv_1);

  // lane byte-slot inside a 64B row span: pixel (q&1), half (q>>1)
  const __half* bvq = pyr + (long)v * PYR_PX * FD + ((q & 1) * 16 + (q >> 1) * 8);

  // ---- batch-issue all 8 row loads; pin with sched_barrier ----
  uint4 dA = *(const uint4*)(bvq + (long)oA * FD);
  uint4 dB = *(const uint4*)(bvq + (long)oB * FD);
  uint4 dC = *(const uint4*)(bvq + (long)oC * FD);
  uint4 dD = *(const uint4*)(bvq + (long)oD * FD);
  uint4 dE = *(const uint4*)(bvq + (long)oE * FD);
  uint4 dF = *(const uint4*)(bvq + (long)oF * FD);
  uint4 dG = *(const uint4*)(bvq + (long)oG * FD);
  uint4 dH = *(const uint4*)(bvq + (long)oH * FD);
  __builtin_amdgcn_sched_barrier(0);

  __half2 z = __float2half2_rn(0.0f);
  __half2 acc0 = z, acc1 = z, acc2 = z, acc3 = z;
  #define ACC8(D, W) { const __half2* hh = (const __half2*)&(D);      \
    acc0 = __hfma2(hh[0], (W), acc0); acc1 = __hfma2(hh[1], (W), acc1); \
    acc2 = __hfma2(hh[2], (W), acc2); acc3 = __hfma2(hh[3], (W), acc3); }
  ACC8(dA, wA) ACC8(dB, wB) ACC8(dC, wC) ACC8(dD, wD)
  ACC8(dE, wE) ACC8(dF, wF) ACC8(dG, wG) ACC8(dH, wH)
  #undef ACC8

  // combine the two pixels of the bilinear x-span (lanes q and q^1)
  int a0 = *(int*)&acc0, a1 = *(int*)&acc1;
  int a2 = *(int*)&acc2, a3 = *(int*)&acc3;
  int b0 = __shfl_xor(a0, 1), b1 = __shfl_xor(a1, 1);
  int b2 = __shfl_xor(a2, 1), b3 = __shfl_xor(a3, 1);
  acc0 = __hadd2(acc0, *(__half2*)&b0);
  acc1 = __hadd2(acc1, *(__half2*)&b1);
  acc2 = __hadd2(acc2, *(__half2*)&b2);
  acc3 = __hadd2(acc3, *(__half2*)&b3);

  __half2 s0 = qodd ? acc2 : acc0;
  __half2 s1 = qodd ? acc3 : acc1;
  float2 f0 = __half22float2(s0);
  float2 f1 = __half22float2(s1);
  *(float4*)(out + ((long)n * NV + v) * FD + q * 4) =
      make_float4(f0.x, f0.y, f1.x, f1.y);
}

extern "C" void kernel_launch(void* const* d_in, const int* in_sizes, int n_in,
                              void* d_out, int out_size, void* d_ws, size_t ws_size,
                              hipStream_t stream)
{
  const float* means = (const float*)d_in[0];
  const float* covs  = (const float*)d_in[1];
  const float* fm    = (const float*)d_in[2];
  float* out = (float*)d_out;
  __half* pyr = (__half*)d_ws;
  float4* pl  = (float4*)((char*)d_ws + PYR_BYTES);

  build_all<<<NV * 256, 256, 0, stream>>>(fm, pyr);
  {
    int tB = NV * 8 * 2040;    // levels 4..6 from 3
    pool_hN<3, 3><<<(tB + 255) / 256, 256, 0, stream>>>(pyr);
    int tC = NV * 4 * 2040;    // level 7 from 6
    pool_hN<6, 1><<<(tC + 255) / 256, 256, 0, stream>>>(pyr);
  }
  proj_kernel<<<(NS + 255) / 256, 256, 0, stream>>>(means, covs, pl);

  interp6<<<40960, 256, 0, stream>>>(pl, pyr, out);
}

// Round 11
// 271.162 us; speedup vs baseline: 1.1656x; 1.0091x over previous
//
#include <hip/hip_runtime.h>
#include <hip/hip_fp16.h>

// RipEncoding, round 11: + alignment-duplicate (1px-x-shifted copy) of hot
// planes (l1,l2 in [2,5]^2) so odd-ix0 taps hit ONE cache line instead of two.
//
// ws layout: [0, 332928000)            fp16 pyramid (10 x 1020x1020 x 16 halfs)
//            [332928000, +18432000)    dup region (10 x 240x240 px, shifted)
//            [351360000, +41943040)    float4 proj table [v][n]

#define NV 10
#define FD 16
#define NS 262144          // 2^18
#define PYR_PX 1040400L    // 1020*1020 pixels per vertex
#define PYR_BYTES 332928000L
#define DUP0_PX 10404000   // = NV*PYR_PX, pixel index where dup region starts
#define DUP_VPX 57600      // 240*240 dup pixels per vertex
#define OFF_PL 351360000L  // PYR_BYTES + NV*DUP_VPX*32

__constant__ float c_P[NV][2][3] = {
  {{-0.7071067811865476f, 0.7071067811865476f, 0.0f},
   {-0.4082482904638631f,-0.4082482904638631f, 0.8164965809277261f}},
  {{-0.7071067811865476f, 0.7071067811865476f, 0.0f},
   { 0.4082482904638631f, 0.4082482904638631f, 0.8164965809277261f}},
  {{ 0.7071067811865476f, 0.7071067811865476f, 0.0f},
   {-0.4082482904638631f, 0.4082482904638631f, 0.8164965809277261f}},
  {{ 0.7071067811865476f, 0.7071067811865476f, 0.0f},
   { 0.4082482904638631f,-0.4082482904638631f, 0.8164965809277261f}},
  {{-1.0f, 0.0f, 0.0f},
   { 0.0f,-0.3568220897730899f, 0.9341723589627157f}},
  {{-1.0f, 0.0f, 0.0f},
   { 0.0f, 0.3568220897730899f, 0.9341723589627157f}},
  {{ 0.0f, 1.0f, 0.0f},
   {-0.9341723589627157f, 0.0f, 0.3568220897730899f}},
  {{ 0.0f, 1.0f, 0.0f},
   { 0.9341723589627157f, 0.0f, 0.3568220897730899f}},
  {{-0.3568220897730899f, 0.9341723589627157f, 0.0f},
   { 0.0f, 0.0f, 1.0f}},
  {{ 0.3568220897730899f, 0.9341723589627157f, 0.0f},
   { 0.0f, 0.0f, 1.0f}},
};

__constant__ int c_CW[8] = {0, 512, 768, 896, 960, 992, 1008, 1016};

// arithmetic plane offset: CW[l] = 1024 - (1024>>l)
__device__ __forceinline__ int offp_a(int l1, int l2) {
  return 1044480 - (1020 << (10 - l1)) + ((1024 - (1024 >> l2)) << (9 - l1));
}

__device__ __forceinline__ uint4 havg(uint4 a, uint4 c, __half2 hhalf) {
  uint4 res;
  __half2* rr = (__half2*)&res;
  const __half2* ha = (const __half2*)&a;
  const __half2* hc = (const __half2*)&c;
  #pragma unroll
  for (int j = 0; j < 4; ++j) rr[j] = __hmul2(__hadd2(ha[j], hc[j]), hhalf);
  return res;
}

// ---- fused build: one block per (v, 8-row band, 128-px strip) ----
__global__ __launch_bounds__(256) void build_all(const float* __restrict__ fm,
                                                 __half* __restrict__ pyr)
{
  __shared__ uint4 ldsA[2048];   // 32 KB: tiles for even l1 (0,2,4,6)
  __shared__ uint4 ldsB[1024];   // 16 KB: tiles for odd l1 (1,3,5,7)
  int bid = blockIdx.x;
  int v = bid >> 8;              // 256 blocks per vertex
  int rem = bid & 255;
  int b = rem >> 2;              // band: rows [8b, 8b+8) of full-height planes
  int s = rem & 3;               // x-strip: fm px [128s, 128s+128)
  int t = threadIdx.x;

  __half* bv = pyr + (long)v * PYR_PX * FD;
  uint4* bv4 = (uint4*)bv;       // 2 uint4 per pixel
  const __half2 hhalf = __floats2half2_rn(0.5f, 0.5f);

  // phase 0: load 8x128 f32 strip, convert, write (0,0), stage LDS A
  {
    const float4* src = (const float4*)(fm +
        (((long)v * 512 + b * 8) * 512 + s * 128) * FD);
    uint2* ldsu2 = (uint2*)ldsA;
    uint2* g0 = (uint2*)bv;      // plane (0,0) at pixel offset 0
    #pragma unroll
    for (int i = 0; i < 16; ++i) {
      int u = t + 256 * i;           // 4096 float4 units
      int r = u >> 9;                // 512 float4 per strip-row
      int f4 = u & 511;
      int px = f4 >> 2, q = f4 & 3;
      float4 d = src[(long)r * 2048 + f4];   // fm row stride = 2048 float4
      __half2 h0 = __floats2half2_rn(d.x, d.y);
      __half2 h1 = __floats2half2_rn(d.z, d.w);
      uint2 val;
      val.x = *(unsigned*)&h0; val.y = *(unsigned*)&h1;
      ldsu2[(r * 128 + px) * 4 + q] = val;
      g0[((long)(b * 8 + r) * 512 + s * 128 + px) * 4 + q] = val;
    }
  }
  __syncthreads();

  #pragma unroll
  for (int l1 = 0; l1 < 8; ++l1) {
    uint4* cur = (l1 & 1) ? ldsB : ldsA;
    const int Wc = 128 >> l1;          // strip-local width at l1

    // width-pool l1 -> l1+1 (LDS + global (l1+1, 0))
    if (l1 < 7) {
      uint4* nxt = (l1 & 1) ? ldsA : ldsB;
      const int Wn = Wc >> 1;
      const int units = 8 * Wn * 2;
      const int Wgn = 512 >> (l1 + 1);
      const int colbase = offp_a(l1 + 1, 0) + s * Wn;
      for (int u = t; u < units; u += 256) {
        int k = u & 1;
        int xr = u >> 1;
        int x = xr & (Wn - 1);
        int r = xr >> (6 - l1);        // xr / Wn, Wn = 64>>l1
        uint4 a = cur[(r * Wc + 2 * x) * 2 + k];
        uint4 c = cur[(r * Wc + 2 * x + 1) * 2 + k];
        uint4 res = havg(a, c, hhalf);
        nxt[(r * Wn + x) * 2 + k] = res;
        bv4[(long)(colbase + (b * 8 + r) * Wgn + x) * 2 + k] = res;
      }
    }

    // height-pool cur tile -> global (l1, 1..3)
    {
      const int slots = Wc * 2;
      if (t < slots) {
        int k = t & 1, x = t >> 1;
        const int Wg = 512 >> l1;
        uint4 r0 = cur[(0 * Wc + x) * 2 + k];
        uint4 r1 = cur[(1 * Wc + x) * 2 + k];
        uint4 r2 = cur[(2 * Wc + x) * 2 + k];
        uint4 r3 = cur[(3 * Wc + x) * 2 + k];
        uint4 r4 = cur[(4 * Wc + x) * 2 + k];
        uint4 r5 = cur[(5 * Wc + x) * 2 + k];
        uint4 r6 = cur[(6 * Wc + x) * 2 + k];
        uint4 r7 = cur[(7 * Wc + x) * 2 + k];
        uint4 a0 = havg(r0, r1, hhalf), a1 = havg(r2, r3, hhalf);
        uint4 a2 = havg(r4, r5, hhalf), a3 = havg(r6, r7, hhalf);
        uint4 b0 = havg(a0, a1, hhalf), b1 = havg(a2, a3, hhalf);
        uint4 c0 = havg(b0, b1, hhalf);
        int gx = s * Wc + x;
        long p1 = (long)offp_a(l1, 1) + (long)(b * 4) * Wg + gx;
        bv4[p1 * 2 + k] = a0;
        bv4[(p1 + Wg) * 2 + k] = a1;
        bv4[(p1 + 2 * Wg) * 2 + k] = a2;
        bv4[(p1 + 3 * Wg) * 2 + k] = a3;
        long p2 = (long)offp_a(l1, 2) + (long)(b * 2) * Wg + gx;
        bv4[p2 * 2 + k] = b0;
        bv4[(p2 + Wg) * 2 + k] = b1;
        long p3 = (long)offp_a(l1, 3) + (long)b * Wg + gx;
        bv4[p3 * 2 + k] = c0;
      }
    }
    __syncthreads();
  }
}

// ---- pool tail: levels (l1, L2SRC+1..L2SRC+NLEV) from (l1, L2SRC) ----
template<int L2SRC, int NLEV>
__global__ __launch_bounds__(256) void pool_hN(__half* __restrict__ pyr)
{
  constexpr int R = 1 << NLEV;
  constexpr int HL = 512 >> (L2SRC + NLEV);     // rows of the last level
  int total = NV * HL * 2040;
  int t = blockIdx.x * 256 + threadIdx.x;
  if (t >= total) return;
  int u = t % 2040;
  int r2 = t / 2040;
  int c = u >> 1, k = u & 1;          // virtual column, 16B slot
  int y = r2 % HL;
  int v = r2 / HL;
  int l1 = 0;
  #pragma unroll
  for (int i = 1; i < 8; ++i) l1 += (c >= c_CW[i]) ? 1 : 0;
  int x = c - c_CW[l1];
  int W = 512 >> l1;
  __half* bv = pyr + (long)v * PYR_PX * FD;
  const __half* src = bv + (long)offp_a(l1, L2SRC) * FD;

  uint4 d[R];
  long base = ((long)(y * R) * W + x) * FD + k * 8;
  #pragma unroll
  for (int r = 0; r < R; ++r)
    d[r] = *(const uint4*)(src + base + (long)r * W * FD);

  const __half2 hhalf = __floats2half2_rn(0.5f, 0.5f);
  #pragma unroll
  for (int lev = 1; lev <= NLEV; ++lev) {
    int cnt = R >> lev;
    __half* dst = bv + (long)offp_a(l1, L2SRC + lev) * FD;
    #pragma unroll
    for (int r = 0; r < cnt; ++r) {
      d[r] = havg(d[2 * r], d[2 * r + 1], hhalf);
      *(uint4*)(dst + (((long)(y * cnt + r)) * W + x) * FD + k * 8) = d[r];
    }
  }
}

// ---- dup build: shifted copy of planes (l1,l2) in [2,5]^2 ----
// dup[v][l1][l2][y][x] = pyr[v][l1][l2][y][min(x+1, W-1)]
__global__ __launch_bounds__(256) void build_dup(__half* __restrict__ pyr)
{
  int cb = blockIdx.y;
  int l1 = 2 + (cb >> 2), l2 = 2 + (cb & 3);
  int W = 512 >> l1, H = 512 >> l2;
  int units = NV * W * H * 2;
  int gx = blockIdx.x * 256 + threadIdx.x;
  if (gx >= units) return;
  int k = gx & 1;
  int p = gx >> 1;
  int x = p & (W - 1);
  int r = p >> (9 - l1);
  int y = r & (H - 1);
  int v = r >> (9 - l2);
  long srcPx = (long)v * PYR_PX + offp_a(l1, l2) + y * W + min(x + 1, W - 1);
  int Ad = 61440 - (245760 >> l1);        // 240*(256 - (1024>>l1))
  int Bd = 256 - (1024 >> l2);
  long dstPx = (long)DUP0_PX + (long)v * DUP_VPX + Ad + ((Bd + y) << (9 - l1)) + x;
  const uint4* src = (const uint4*)(pyr + srcPx * FD);
  uint4* dst = (uint4*)(pyr + dstPx * FD);
  dst[k] = src[k];
}

// ---- projection/level precompute: one thread per sample ----
__global__ __launch_bounds__(256) void proj_kernel(const float* __restrict__ means,
                                                   const float* __restrict__ covs,
                                                   float4* __restrict__ pl)
{
  int n = blockIdx.x * 256 + threadIdx.x;
  if (n >= NS) return;
  float m0 = means[3 * n], m1 = means[3 * n + 1], m2 = means[3 * n + 2];
  const float* C = covs + 9L * n;
  float c0 = C[0], c1 = C[1], c2 = C[2];
  float c3 = C[3], c4 = C[4], c5 = C[5];
  float c6 = C[6], c7 = C[7], c8 = C[8];
  #pragma unroll
  for (int v = 0; v < NV; ++v) {
    float p00 = c_P[v][0][0], p01 = c_P[v][0][1], p02 = c_P[v][0][2];
    float p10 = c_P[v][1][0], p11 = c_P[v][1][1], p12 = c_P[v][1][2];
    float cx = m0 * p00 + m1 * p01 + m2 * p02;
    float cy = m0 * p10 + m1 * p11 + m2 * p12;
    float t0 = c0 * p00 + c1 * p01 + c2 * p02;
    float t1 = c3 * p00 + c4 * p01 + c5 * p02;
    float t2 = c6 * p00 + c7 * p01 + c8 * p02;
    float s2x = p00 * t0 + p01 * t1 + p02 * t2;
    t0 = c0 * p10 + c1 * p11 + c2 * p12;
    t1 = c3 * p10 + c4 * p11 + c5 * p12;
    t2 = c6 * p10 + c7 * p11 + c8 * p12;
    float s2y = p10 * t0 + p11 * t1 + p12 * t2;
    float lx = 0.5f * log2f(fmaxf(s2x, 1e-20f)) + 9.0f;
    float ly = 0.5f * log2f(fmaxf(s2y, 1e-20f)) + 9.0f;
    lx = fminf(fmaxf(lx, 0.0f), 7.0f);
    ly = fminf(fmaxf(ly, 0.0f), 7.0f);
    pl[(long)v * NS + n] = make_float4(cx, cy, lx, ly);
  }
}

// ---- interp: 4 threads/pair, 64B row loads, dup-aligned odd spans ----
__global__ __launch_bounds__(256) void interp7(const float4* __restrict__ pl,
                                               const __half* __restrict__ pyr,
                                               float* __restrict__ out)
{
  int bid = blockIdx.x;
  int swz = (bid & 7) * 5120 + (bid >> 3);    // 40960/8 = 5120 blocks per XCD
  int t = swz * 256 + threadIdx.x;
  int q = t & 3;
  int vlow = (t >> 2) & 1;
  int n = (t >> 3) & (NS - 1);
  int v2 = t >> 21;
  int v = v2 * 2 + vlow;

  float4 p = pl[(long)v * NS + n];
  float cx = p.x, cy = p.y, lx = p.z, ly = p.w;
  int l1f = (int)lx, l2f = (int)ly;
  float wx = lx - (float)l1f, wy = ly - (float)l2f;
  int l1c = min(l1f + 1, 7);
  int l2c = min(l2f + 1, 7);

  bool qodd = (q & 1);
  int dupRel = DUP0_PX + v * DUP_VPX - v * 1040400;  // dup base rel. to bv

  // ---- u-side, scalar per distinct l1 ----
  int sh_0 = 9 - l1f;
  int Ar_0 = 1044480 - (1020 << (10 - l1f));
  float u0 = (cx * 0.5f + 0.5f) * (float)(1 << sh_0) - 0.5f;
  float uf0 = floorf(u0);
  float fu0 = u0 - uf0;
  int iu0 = (int)uf0;
  bool e0 = (iu0 < 0) || (iu0 >= (1 << sh_0) - 1);
  int ix_0 = min(max(iu0, 0), (1 << sh_0) - 1);
  float wxl_0 = qodd ? (e0 ? 0.0f : fu0) : (e0 ? 1.0f : 1.0f - fu0);
  int pOdd_0 = ix_0 & 1;
  int Ad_0 = 61440 - (245760 >> l1f);
  int inR1_0 = ((unsigned)(l1f - 2) <= 3u) ? 1 : 0;

  int sh_1 = 9 - l1c;
  int Ar_1 = 1044480 - (1020 << (10 - l1c));
  float u1 = (cx * 0.5f + 0.5f) * (float)(1 << sh_1) - 0.5f;
  float uf1 = floorf(u1);
  float fu1 = u1 - uf1;
  int iu1 = (int)uf1;
  bool e1 = (iu1 < 0) || (iu1 >= (1 << sh_1) - 1);
  int ix_1 = min(max(iu1, 0), (1 << sh_1) - 1);
  float wxl_1 = qodd ? (e1 ? 0.0f : fu1) : (e1 ? 1.0f : 1.0f - fu1);
  int pOdd_1 = ix_1 & 1;
  int Ad_1 = 61440 - (245760 >> l1c);
  int inR1_1 = ((unsigned)(l1c - 2) <= 3u) ? 1 : 0;

  float wl1_0 = 1.0f - wx, wl1_1 = wx;

  // ---- v-side, scalar per distinct l2 ----
  int H0 = 512 >> l2f;
  float vv0 = (cy * 0.5f + 0.5f) * (float)H0 - 0.5f;
  float vf0 = floorf(vv0);
  float fv_0 = vv0 - vf0;
  int iv0 = (int)vf0;
  int iy_0 = min(max(iv0, 0), H0 - 1);
  int dy_0 = min(max(iv0 + 1, 0), H0 - 1) - iy_0;
  int Bv_0 = 1024 - (1024 >> l2f);
  int Bd_0 = 256 - (1024 >> l2f);
  int inR2_0 = ((unsigned)(l2f - 2) <= 3u) ? 1 : 0;

  int H1 = 512 >> l2c;
  float vv1 = (cy * 0.5f + 0.5f) * (float)H1 - 0.5f;
  float vf1 = floorf(vv1);
  float fv_1 = vv1 - vf1;
  int iv1 = (int)vf1;
  int iy_1 = min(max(iv1, 0), H1 - 1);
  int dy_1 = min(max(iv1 + 1, 0), H1 - 1) - iy_1;
  int Bv_1 = 1024 - (1024 >> l2c);
  int Bd_1 = 256 - (1024 >> l2c);
  int inR2_1 = ((unsigned)(l2c - 2) <= 3u) ? 1 : 0;

  float wl2_0 = 1.0f - wy, wl2_1 = wy;

  // ---- combo offsets: pick dup (aligned) when ix odd and levels hot ----
  bool s00 = pOdd_0 && inR1_0 && inR2_0;
  int oA = s00 ? (dupRel + Ad_0 + ((Bd_0 + iy_0) << sh_0) + ix_0 - 1)
               : (Ar_0 + ((Bv_0 + iy_0) << sh_0) + ix_0);
  int oB = oA + (dy_0 << sh_0);
  bool s01 = pOdd_0 && inR1_0 && inR2_1;
  int oC = s01 ? (dupRel + Ad_0 + ((Bd_1 + iy_1) << sh_0) + ix_0 - 1)
               : (Ar_0 + ((Bv_1 + iy_1) << sh_0) + ix_0);
  int oD = oC + (dy_1 << sh_0);
  bool s10 = pOdd_1 && inR1_1 && inR2_0;
  int oE = s10 ? (dupRel + Ad_1 + ((Bd_0 + iy_0) << sh_1) + ix_1 - 1)
               : (Ar_1 + ((Bv_0 + iy_0) << sh_1) + ix_1);
  int oF = oE + (dy_0 << sh_1);
  bool s11 = pOdd_1 && inR1_1 && inR2_1;
  int oG = s11 ? (dupRel + Ad_1 + ((Bd_1 + iy_1) << sh_1) + ix_1 - 1)
               : (Ar_1 + ((Bv_1 + iy_1) << sh_1) + ix_1);
  int oH = oG + (dy_1 << sh_1);

  float wb00 = wl1_0 * wl2_0 * wxl_0;
  float wb01 = wl1_0 * wl2_1 * wxl_0;
  float wb10 = wl1_1 * wl2_0 * wxl_1;
  float wb11 = wl1_1 * wl2_1 * wxl_1;
  __half2 wA = __float2half2_rn(wb00 * (1.0f - fv_0));
  __half2 wB = __float2half2_rn(wb00 * fv_0);
  __half2 wC = __float2half2_rn(wb01 * (1.0f - fv_1));
  __half2 wD = __float2half2_rn(wb01 * fv_1);
  __half2 wE = __float2half2_rn(wb10 * (1.0f - fv_0));
  __half2 wF = __float2half2_rn(wb10 * fv_0);
  __half2 wG = __float2half2_rn(wb11 * (1.0f - fv_1));
  __half2 wH = __float2half2_rn(wb11 * fv_1);

  // lane byte-slot inside a 64B row span: pixel (q&1), half (q>>1)
  const __half* bvq = pyr + (long)v * PYR_PX * FD + ((q & 1) * 16 + (q >> 1) * 8);

  // ---- batch-issue all 8 row loads; pin with sched_barrier ----
  uint4 dA = *(const uint4*)(bvq + (long)oA * FD);
  uint4 dB = *(const uint4*)(bvq + (long)oB * FD);
  uint4 dC = *(const uint4*)(bvq + (long)oC * FD);
  uint4 dD = *(const uint4*)(bvq + (long)oD * FD);
  uint4 dE = *(const uint4*)(bvq + (long)oE * FD);
  uint4 dF = *(const uint4*)(bvq + (long)oF * FD);
  uint4 dG = *(const uint4*)(bvq + (long)oG * FD);
  uint4 dH = *(const uint4*)(bvq + (long)oH * FD);
  __builtin_amdgcn_sched_barrier(0);

  __half2 z = __float2half2_rn(0.0f);
  __half2 acc0 = z, acc1 = z, acc2 = z, acc3 = z;
  #define ACC8(D, W) { const __half2* hh = (const __half2*)&(D);      \
    acc0 = __hfma2(hh[0], (W), acc0); acc1 = __hfma2(hh[1], (W), acc1); \
    acc2 = __hfma2(hh[2], (W), acc2); acc3 = __hfma2(hh[3], (W), acc3); }
  ACC8(dA, wA) ACC8(dB, wB) ACC8(dC, wC) ACC8(dD, wD)
  ACC8(dE, wE) ACC8(dF, wF) ACC8(dG, wG) ACC8(dH, wH)
  #undef ACC8

  // combine the two pixels of the bilinear x-span (lanes q and q^1)
  int a0 = *(int*)&acc0, a1 = *(int*)&acc1;
  int a2 = *(int*)&acc2, a3 = *(int*)&acc3;
  int b0 = __shfl_xor(a0, 1), b1 = __shfl_xor(a1, 1);
  int b2 = __shfl_xor(a2, 1), b3 = __shfl_xor(a3, 1);
  acc0 = __hadd2(acc0, *(__half2*)&b0);
  acc1 = __hadd2(acc1, *(__half2*)&b1);
  acc2 = __hadd2(acc2, *(__half2*)&b2);
  acc3 = __hadd2(acc3, *(__half2*)&b3);

  __half2 s0 = qodd ? acc2 : acc0;
  __half2 s1 = qodd ? acc3 : acc1;
  float2 f0 = __half22float2(s0);
  float2 f1 = __half22float2(s1);
  *(float4*)(out + ((long)n * NV + v) * FD + q * 4) =
      make_float4(f0.x, f0.y, f1.x, f1.y);
}

extern "C" void kernel_launch(void* const* d_in, const int* in_sizes, int n_in,
                              void* d_out, int out_size, void* d_ws, size_t ws_size,
                              hipStream_t stream)
{
  const float* means = (const float*)d_in[0];
  const float* covs  = (const float*)d_in[1];
  const float* fm    = (const float*)d_in[2];
  float* out = (float*)d_out;
  __half* pyr = (__half*)d_ws;
  float4* pl  = (float4*)((char*)d_ws + OFF_PL);

  build_all<<<NV * 256, 256, 0, stream>>>(fm, pyr);
  {
    int tB = NV * 8 * 2040;    // levels 4..6 from 3
    pool_hN<3, 3><<<(tB + 255) / 256, 256, 0, stream>>>(pyr);
    int tC = NV * 4 * 2040;    // level 7 from 6
    pool_hN<6, 1><<<(tC + 255) / 256, 256, 0, stream>>>(pyr);
  }
  {
    dim3 g(1280, 16, 1);       // 1280 covers the largest (128x128) combo
    build_dup<<<g, 256, 0, stream>>>(pyr);
  }
  proj_kernel<<<(NS + 255) / 256, 256, 0, stream>>>(means, covs, pl);

  interp7<<<40960, 256, 0, stream>>>(pl, pyr, out);
}

// Round 12
// 251.240 us; speedup vs baseline: 1.2580x; 1.0793x over previous
//
#include <hip/hip_runtime.h>
#include <hip/hip_fp16.h>

// RipEncoding, round 12: 2-pairs-per-thread interp (16 loads in flight),
// plane (0,0) read directly from fm (never materialized, -84 MB writes).
//
// ws layout: [0, 332928000)            fp16 pyramid (10 x 1020x1020 x 16 halfs)
//            [332928000, +18432000)    dup region (10 x 240x240 px, x-shifted)
//            [351360000, +41943040)    float4 proj table [v][n]

#define NV 10
#define FD 16
#define NS 262144          // 2^18
#define HALF_NS 131072     // 2^17
#define PYR_PX 1040400L    // 1020*1020 pixels per vertex
#define PYR_BYTES 332928000L
#define DUP0_PX 10404000   // = NV*PYR_PX, pixel index where dup region starts
#define DUP_VPX 57600      // 240*240 dup pixels per vertex
#define OFF_PL 351360000L  // PYR_BYTES + NV*DUP_VPX*32

__constant__ float c_P[NV][2][3] = {
  {{-0.7071067811865476f, 0.7071067811865476f, 0.0f},
   {-0.4082482904638631f,-0.4082482904638631f, 0.8164965809277261f}},
  {{-0.7071067811865476f, 0.7071067811865476f, 0.0f},
   { 0.4082482904638631f, 0.4082482904638631f, 0.8164965809277261f}},
  {{ 0.7071067811865476f, 0.7071067811865476f, 0.0f},
   {-0.4082482904638631f, 0.4082482904638631f, 0.8164965809277261f}},
  {{ 0.7071067811865476f, 0.7071067811865476f, 0.0f},
   { 0.4082482904638631f,-0.4082482904638631f, 0.8164965809277261f}},
  {{-1.0f, 0.0f, 0.0f},
   { 0.0f,-0.3568220897730899f, 0.9341723589627157f}},
  {{-1.0f, 0.0f, 0.0f},
   { 0.0f, 0.3568220897730899f, 0.9341723589627157f}},
  {{ 0.0f, 1.0f, 0.0f},
   {-0.9341723589627157f, 0.0f, 0.3568220897730899f}},
  {{ 0.0f, 1.0f, 0.0f},
   { 0.9341723589627157f, 0.0f, 0.3568220897730899f}},
  {{-0.3568220897730899f, 0.9341723589627157f, 0.0f},
   { 0.0f, 0.0f, 1.0f}},
  {{ 0.3568220897730899f, 0.9341723589627157f, 0.0f},
   { 0.0f, 0.0f, 1.0f}},
};

__constant__ int c_CW[8] = {0, 512, 768, 896, 960, 992, 1008, 1016};

// arithmetic plane offset: CW[l] = 1024 - (1024>>l)
__device__ __forceinline__ int offp_a(int l1, int l2) {
  return 1044480 - (1020 << (10 - l1)) + ((1024 - (1024 >> l2)) << (9 - l1));
}

__device__ __forceinline__ uint4 havg(uint4 a, uint4 c, __half2 hhalf) {
  uint4 res;
  __half2* rr = (__half2*)&res;
  const __half2* ha = (const __half2*)&a;
  const __half2* hc = (const __half2*)&c;
  #pragma unroll
  for (int j = 0; j < 4; ++j) rr[j] = __hmul2(__hadd2(ha[j], hc[j]), hhalf);
  return res;
}

// ---- fused build: one block per (v, 8-row band, 128-px strip) ----
// NOTE: plane (0,0) is NOT materialized; interp reads fm directly for it.
__global__ __launch_bounds__(256) void build_all(const float* __restrict__ fm,
                                                 __half* __restrict__ pyr)
{
  __shared__ uint4 ldsA[2048];   // 32 KB: tiles for even l1 (0,2,4,6)
  __shared__ uint4 ldsB[1024];   // 16 KB: tiles for odd l1 (1,3,5,7)
  int bid = blockIdx.x;
  int v = bid >> 8;              // 256 blocks per vertex
  int rem = bid & 255;
  int b = rem >> 2;              // band: rows [8b, 8b+8) of full-height planes
  int s = rem & 3;               // x-strip: fm px [128s, 128s+128)
  int t = threadIdx.x;

  __half* bv = pyr + (long)v * PYR_PX * FD;
  uint4* bv4 = (uint4*)bv;       // 2 uint4 per pixel
  const __half2 hhalf = __floats2half2_rn(0.5f, 0.5f);

  // phase 0: load 8x128 f32 strip, convert, stage LDS A
  {
    const float4* src = (const float4*)(fm +
        (((long)v * 512 + b * 8) * 512 + s * 128) * FD);
    uint2* ldsu2 = (uint2*)ldsA;
    #pragma unroll
    for (int i = 0; i < 16; ++i) {
      int u = t + 256 * i;           // 4096 float4 units
      int r = u >> 9;                // 512 float4 per strip-row
      int f4 = u & 511;
      int px = f4 >> 2, qq = f4 & 3;
      float4 d = src[(long)r * 2048 + f4];   // fm row stride = 2048 float4
      __half2 h0 = __floats2half2_rn(d.x, d.y);
      __half2 h1 = __floats2half2_rn(d.z, d.w);
      uint2 val;
      val.x = *(unsigned*)&h0; val.y = *(unsigned*)&h1;
      ldsu2[(r * 128 + px) * 4 + qq] = val;
    }
  }
  __syncthreads();

  #pragma unroll
  for (int l1 = 0; l1 < 8; ++l1) {
    uint4* cur = (l1 & 1) ? ldsB : ldsA;
    const int Wc = 128 >> l1;          // strip-local width at l1

    // width-pool l1 -> l1+1 (LDS + global (l1+1, 0))
    if (l1 < 7) {
      uint4* nxt = (l1 & 1) ? ldsA : ldsB;
      const int Wn = Wc >> 1;
      const int units = 8 * Wn * 2;
      const int Wgn = 512 >> (l1 + 1);
      const int colbase = offp_a(l1 + 1, 0) + s * Wn;
      for (int u = t; u < units; u += 256) {
        int k = u & 1;
        int xr = u >> 1;
        int x = xr & (Wn - 1);
        int r = xr >> (6 - l1);        // xr / Wn, Wn = 64>>l1
        uint4 a = cur[(r * Wc + 2 * x) * 2 + k];
        uint4 c = cur[(r * Wc + 2 * x + 1) * 2 + k];
        uint4 res = havg(a, c, hhalf);
        nxt[(r * Wn + x) * 2 + k] = res;
        bv4[(long)(colbase + (b * 8 + r) * Wgn + x) * 2 + k] = res;
      }
    }

    // height-pool cur tile -> global (l1, 1..3)
    {
      const int slots = Wc * 2;
      if (t < slots) {
        int k = t & 1, x = t >> 1;
        const int Wg = 512 >> l1;
        uint4 r0 = cur[(0 * Wc + x) * 2 + k];
        uint4 r1 = cur[(1 * Wc + x) * 2 + k];
        uint4 r2 = cur[(2 * Wc + x) * 2 + k];
        uint4 r3 = cur[(3 * Wc + x) * 2 + k];
        uint4 r4 = cur[(4 * Wc + x) * 2 + k];
        uint4 r5 = cur[(5 * Wc + x) * 2 + k];
        uint4 r6 = cur[(6 * Wc + x) * 2 + k];
        uint4 r7 = cur[(7 * Wc + x) * 2 + k];
        uint4 a0 = havg(r0, r1, hhalf), a1 = havg(r2, r3, hhalf);
        uint4 a2 = havg(r4, r5, hhalf), a3 = havg(r6, r7, hhalf);
        uint4 b0 = havg(a0, a1, hhalf), b1 = havg(a2, a3, hhalf);
        uint4 c0 = havg(b0, b1, hhalf);
        int gx = s * Wc + x;
        long p1 = (long)offp_a(l1, 1) + (long)(b * 4) * Wg + gx;
        bv4[p1 * 2 + k] = a0;
        bv4[(p1 + Wg) * 2 + k] = a1;
        bv4[(p1 + 2 * Wg) * 2 + k] = a2;
        bv4[(p1 + 3 * Wg) * 2 + k] = a3;
        long p2 = (long)offp_a(l1, 2) + (long)(b * 2) * Wg + gx;
        bv4[p2 * 2 + k] = b0;
        bv4[(p2 + Wg) * 2 + k] = b1;
        long p3 = (long)offp_a(l1, 3) + (long)b * Wg + gx;
        bv4[p3 * 2 + k] = c0;
      }
    }
    __syncthreads();
  }
}

// ---- pool tail: levels (l1, L2SRC+1..L2SRC+NLEV) from (l1, L2SRC) ----
template<int L2SRC, int NLEV>
__global__ __launch_bounds__(256) void pool_hN(__half* __restrict__ pyr)
{
  constexpr int R = 1 << NLEV;
  constexpr int HL = 512 >> (L2SRC + NLEV);     // rows of the last level
  int total = NV * HL * 2040;
  int t = blockIdx.x * 256 + threadIdx.x;
  if (t >= total) return;
  int u = t % 2040;
  int r2 = t / 2040;
  int c = u >> 1, k = u & 1;          // virtual column, 16B slot
  int y = r2 % HL;
  int v = r2 / HL;
  int l1 = 0;
  #pragma unroll
  for (int i = 1; i < 8; ++i) l1 += (c >= c_CW[i]) ? 1 : 0;
  int x = c - c_CW[l1];
  int W = 512 >> l1;
  __half* bv = pyr + (long)v * PYR_PX * FD;
  const __half* src = bv + (long)offp_a(l1, L2SRC) * FD;

  uint4 d[R];
  long base = ((long)(y * R) * W + x) * FD + k * 8;
  #pragma unroll
  for (int r = 0; r < R; ++r)
    d[r] = *(const uint4*)(src + base + (long)r * W * FD);

  const __half2 hhalf = __floats2half2_rn(0.5f, 0.5f);
  #pragma unroll
  for (int lev = 1; lev <= NLEV; ++lev) {
    int cnt = R >> lev;
    __half* dst = bv + (long)offp_a(l1, L2SRC + lev) * FD;
    #pragma unroll
    for (int r = 0; r < cnt; ++r) {
      d[r] = havg(d[2 * r], d[2 * r + 1], hhalf);
      *(uint4*)(dst + (((long)(y * cnt + r)) * W + x) * FD + k * 8) = d[r];
    }
  }
}

// ---- dup build: x-shifted copy of planes (l1,l2) in [2,5]^2 ----
__global__ __launch_bounds__(256) void build_dup(__half* __restrict__ pyr)
{
  int cb = blockIdx.y;
  int l1 = 2 + (cb >> 2), l2 = 2 + (cb & 3);
  int W = 512 >> l1, H = 512 >> l2;
  int units = NV * W * H * 2;
  int gx = blockIdx.x * 256 + threadIdx.x;
  if (gx >= units) return;
  int k = gx & 1;
  int p = gx >> 1;
  int x = p & (W - 1);
  int r = p >> (9 - l1);
  int y = r & (H - 1);
  int v = r >> (9 - l2);
  long srcPx = (long)v * PYR_PX + offp_a(l1, l2) + y * W + min(x + 1, W - 1);
  int Ad = 61440 - (245760 >> l1);        // 240*(256 - (1024>>l1))
  int Bd = 256 - (1024 >> l2);
  long dstPx = (long)DUP0_PX + (long)v * DUP_VPX + Ad + ((Bd + y) << (9 - l1)) + x;
  const uint4* src = (const uint4*)(pyr + srcPx * FD);
  uint4* dst = (uint4*)(pyr + dstPx * FD);
  dst[k] = src[k];
}

// ---- projection/level precompute: one thread per sample ----
__global__ __launch_bounds__(256) void proj_kernel(const float* __restrict__ means,
                                                   const float* __restrict__ covs,
                                                   float4* __restrict__ pl)
{
  int n = blockIdx.x * 256 + threadIdx.x;
  if (n >= NS) return;
  float m0 = means[3 * n], m1 = means[3 * n + 1], m2 = means[3 * n + 2];
  const float* C = covs + 9L * n;
  float c0 = C[0], c1 = C[1], c2 = C[2];
  float c3 = C[3], c4 = C[4], c5 = C[5];
  float c6 = C[6], c7 = C[7], c8 = C[8];
  #pragma unroll
  for (int v = 0; v < NV; ++v) {
    float p00 = c_P[v][0][0], p01 = c_P[v][0][1], p02 = c_P[v][0][2];
    float p10 = c_P[v][1][0], p11 = c_P[v][1][1], p12 = c_P[v][1][2];
    float cx = m0 * p00 + m1 * p01 + m2 * p02;
    float cy = m0 * p10 + m1 * p11 + m2 * p12;
    float t0 = c0 * p00 + c1 * p01 + c2 * p02;
    float t1 = c3 * p00 + c4 * p01 + c5 * p02;
    float t2 = c6 * p00 + c7 * p01 + c8 * p02;
    float s2x = p00 * t0 + p01 * t1 + p02 * t2;
    t0 = c0 * p10 + c1 * p11 + c2 * p12;
    t1 = c3 * p10 + c4 * p11 + c5 * p12;
    t2 = c6 * p10 + c7 * p11 + c8 * p12;
    float s2y = p10 * t0 + p11 * t1 + p12 * t2;
    float lx = 0.5f * log2f(fmaxf(s2x, 1e-20f)) + 9.0f;
    float ly = 0.5f * log2f(fmaxf(s2y, 1e-20f)) + 9.0f;
    lx = fminf(fmaxf(lx, 0.0f), 7.0f);
    ly = fminf(fmaxf(ly, 0.0f), 7.0f);
    pl[(long)v * NS + n] = make_float4(cx, cy, lx, ly);
  }
}

// ---- per-pair tap context: named scalar fields only (no arrays) ----
struct Ctx {
  int oA, oB, oC, oD, oE, oF, oG, oH;
  __half2 wA, wB, wC, wD, wE, wF, wG, wH;
  int z00;            // combo A is plane (0,0) -> read from fm
  float fwA, fwB;     // f32 row weights for the fm path
  int ix0, iy0, dy0;  // fm path coords (valid when z00)
};

__device__ __forceinline__ Ctx mk_ctx(const float4 p, const bool qodd,
                                      const int dupRel)
{
  Ctx c;
  float cx = p.x, cy = p.y, lx = p.z, ly = p.w;
  int l1f = (int)lx, l2f = (int)ly;
  float wx = lx - (float)l1f, wy = ly - (float)l2f;
  int l1c = min(l1f + 1, 7);
  int l2c = min(l2f + 1, 7);

  int sh_0 = 9 - l1f;
  int Ar_0 = 1044480 - (1020 << (10 - l1f));
  float u0 = (cx * 0.5f + 0.5f) * (float)(1 << sh_0) - 0.5f;
  float uf0 = floorf(u0);
  float fu0 = u0 - uf0;
  int iu0 = (int)uf0;
  bool e0 = (iu0 < 0) || (iu0 >= (1 << sh_0) - 1);
  int ix_0 = min(max(iu0, 0), (1 << sh_0) - 1);
  float wxl_0 = qodd ? (e0 ? 0.0f : fu0) : (e0 ? 1.0f : 1.0f - fu0);
  int pOdd_0 = ix_0 & 1;
  int Ad_0 = 61440 - (245760 >> l1f);
  int inR1_0 = ((unsigned)(l1f - 2) <= 3u) ? 1 : 0;

  int sh_1 = 9 - l1c;
  int Ar_1 = 1044480 - (1020 << (10 - l1c));
  float u1 = (cx * 0.5f + 0.5f) * (float)(1 << sh_1) - 0.5f;
  float uf1 = floorf(u1);
  float fu1 = u1 - uf1;
  int iu1 = (int)uf1;
  bool e1 = (iu1 < 0) || (iu1 >= (1 << sh_1) - 1);
  int ix_1 = min(max(iu1, 0), (1 << sh_1) - 1);
  float wxl_1 = qodd ? (e1 ? 0.0f : fu1) : (e1 ? 1.0f : 1.0f - fu1);
  int pOdd_1 = ix_1 & 1;
  int Ad_1 = 61440 - (245760 >> l1c);
  int inR1_1 = ((unsigned)(l1c - 2) <= 3u) ? 1 : 0;

  float wl1_0 = 1.0f - wx, wl1_1 = wx;

  int H0 = 512 >> l2f;
  float vv0 = (cy * 0.5f + 0.5f) * (float)H0 - 0.5f;
  float vf0 = floorf(vv0);
  float fv_0 = vv0 - vf0;
  int iv0 = (int)vf0;
  int iy_0 = min(max(iv0, 0), H0 - 1);
  int dy_0 = min(max(iv0 + 1, 0), H0 - 1) - iy_0;
  int Bv_0 = 1024 - (1024 >> l2f);
  int Bd_0 = 256 - (1024 >> l2f);
  int inR2_0 = ((unsigned)(l2f - 2) <= 3u) ? 1 : 0;

  int H1 = 512 >> l2c;
  float vv1 = (cy * 0.5f + 0.5f) * (float)H1 - 0.5f;
  float vf1 = floorf(vv1);
  float fv_1 = vv1 - vf1;
  int iv1 = (int)vf1;
  int iy_1 = min(max(iv1, 0), H1 - 1);
  int dy_1 = min(max(iv1 + 1, 0), H1 - 1) - iy_1;
  int Bv_1 = 1024 - (1024 >> l2c);
  int Bd_1 = 256 - (1024 >> l2c);
  int inR2_1 = ((unsigned)(l2c - 2) <= 3u) ? 1 : 0;

  float wl2_0 = 1.0f - wy, wl2_1 = wy;

  bool s00 = pOdd_0 && inR1_0 && inR2_0;
  c.oA = s00 ? (dupRel + Ad_0 + ((Bd_0 + iy_0) << sh_0) + ix_0 - 1)
             : (Ar_0 + ((Bv_0 + iy_0) << sh_0) + ix_0);
  c.oB = c.oA + (dy_0 << sh_0);
  bool s01 = pOdd_0 && inR1_0 && inR2_1;
  c.oC = s01 ? (dupRel + Ad_0 + ((Bd_1 + iy_1) << sh_0) + ix_0 - 1)
             : (Ar_0 + ((Bv_1 + iy_1) << sh_0) + ix_0);
  c.oD = c.oC + (dy_1 << sh_0);
  bool s10 = pOdd_1 && inR1_1 && inR2_0;
  c.oE = s10 ? (dupRel + Ad_1 + ((Bd_0 + iy_0) << sh_1) + ix_1 - 1)
             : (Ar_1 + ((Bv_0 + iy_0) << sh_1) + ix_1);
  c.oF = c.oE + (dy_0 << sh_1);
  bool s11 = pOdd_1 && inR1_1 && inR2_1;
  c.oG = s11 ? (dupRel + Ad_1 + ((Bd_1 + iy_1) << sh_1) + ix_1 - 1)
             : (Ar_1 + ((Bv_1 + iy_1) << sh_1) + ix_1);
  c.oH = c.oG + (dy_1 << sh_1);

  float wb00 = wl1_0 * wl2_0 * wxl_0;
  float wb01 = wl1_0 * wl2_1 * wxl_0;
  float wb10 = wl1_1 * wl2_0 * wxl_1;
  float wb11 = wl1_1 * wl2_1 * wxl_1;
  c.wA = __float2half2_rn(wb00 * (1.0f - fv_0));
  c.wB = __float2half2_rn(wb00 * fv_0);
  c.wC = __float2half2_rn(wb01 * (1.0f - fv_1));
  c.wD = __float2half2_rn(wb01 * fv_1);
  c.wE = __float2half2_rn(wb10 * (1.0f - fv_0));
  c.wF = __float2half2_rn(wb10 * fv_0);
  c.wG = __float2half2_rn(wb11 * (1.0f - fv_1));
  c.wH = __float2half2_rn(wb11 * fv_1);

  c.z00 = ((l1f | l2f) == 0) ? 1 : 0;
  c.fwA = wb00 * (1.0f - fv_0);
  c.fwB = wb00 * fv_0;
  c.ix0 = ix_0; c.iy0 = iy_0; c.dy0 = dy_0;
  if (c.z00) {                      // combo A unwritten -> zero its weights
    __half2 z = __float2half2_rn(0.0f);
    c.wA = z; c.wB = z;
  }
  return c;
}

// ---- interp: 4 lanes/pair, 2 pairs/thread (16 loads in flight) ----
__global__ __launch_bounds__(256) void interp8(const float4* __restrict__ pl,
                                               const __half* __restrict__ pyr,
                                               const float* __restrict__ fm,
                                               float* __restrict__ out)
{
  int bid = blockIdx.x;
  int swz = (bid & 7) * 2560 + (bid >> 3);    // 20480/8 = 2560 blocks per XCD
  int t = swz * 256 + threadIdx.x;
  int q = t & 3;
  bool qodd = (q & 1);
  int vlow = (t >> 2) & 1;
  int n = (t >> 3) & (HALF_NS - 1);
  int v2 = t >> 20;
  int v = v2 * 2 + vlow;
  int nA = n, nB = n + HALF_NS;
  int dupRel = DUP0_PX + v * DUP_VPX - v * 1040400;

  float4 pA = pl[(long)v * NS + nA];
  float4 pB = pl[(long)v * NS + nB];

  const __half* bvq = pyr + (long)v * PYR_PX * FD + ((q & 1) * 16 + (q >> 1) * 8);

  Ctx cA = mk_ctx(pA, qodd, dupRel);
  uint4 dAA = *(const uint4*)(bvq + (long)cA.oA * FD);
  uint4 dAB = *(const uint4*)(bvq + (long)cA.oB * FD);
  uint4 dAC = *(const uint4*)(bvq + (long)cA.oC * FD);
  uint4 dAD = *(const uint4*)(bvq + (long)cA.oD * FD);
  uint4 dAE = *(const uint4*)(bvq + (long)cA.oE * FD);
  uint4 dAF = *(const uint4*)(bvq + (long)cA.oF * FD);
  uint4 dAG = *(const uint4*)(bvq + (long)cA.oG * FD);
  uint4 dAH = *(const uint4*)(bvq + (long)cA.oH * FD);

  Ctx cB = mk_ctx(pB, qodd, dupRel);
  uint4 dBA = *(const uint4*)(bvq + (long)cB.oA * FD);
  uint4 dBB = *(const uint4*)(bvq + (long)cB.oB * FD);
  uint4 dBC = *(const uint4*)(bvq + (long)cB.oC * FD);
  uint4 dBD = *(const uint4*)(bvq + (long)cB.oD * FD);
  uint4 dBE = *(const uint4*)(bvq + (long)cB.oE * FD);
  uint4 dBF = *(const uint4*)(bvq + (long)cB.oF * FD);
  uint4 dBG = *(const uint4*)(bvq + (long)cB.oG * FD);
  uint4 dBH = *(const uint4*)(bvq + (long)cB.oH * FD);
  __builtin_amdgcn_sched_barrier(0);

  __half2 z = __float2half2_rn(0.0f);
  __half2 aA0 = z, aA1 = z, aA2 = z, aA3 = z;
  __half2 aB0 = z, aB1 = z, aB2 = z, aB3 = z;
  #define ACC8(A0, A1, A2, A3, D, W) { const __half2* hh = (const __half2*)&(D); \
    A0 = __hfma2(hh[0], (W), A0); A1 = __hfma2(hh[1], (W), A1);                   \
    A2 = __hfma2(hh[2], (W), A2); A3 = __hfma2(hh[3], (W), A3); }
  ACC8(aA0,aA1,aA2,aA3, dAA, cA.wA) ACC8(aA0,aA1,aA2,aA3, dAB, cA.wB)
  ACC8(aA0,aA1,aA2,aA3, dAC, cA.wC) ACC8(aA0,aA1,aA2,aA3, dAD, cA.wD)
  ACC8(aA0,aA1,aA2,aA3, dAE, cA.wE) ACC8(aA0,aA1,aA2,aA3, dAF, cA.wF)
  ACC8(aA0,aA1,aA2,aA3, dAG, cA.wG) ACC8(aA0,aA1,aA2,aA3, dAH, cA.wH)
  ACC8(aB0,aB1,aB2,aB3, dBA, cB.wA) ACC8(aB0,aB1,aB2,aB3, dBB, cB.wB)
  ACC8(aB0,aB1,aB2,aB3, dBC, cB.wC) ACC8(aB0,aB1,aB2,aB3, dBD, cB.wD)
  ACC8(aB0,aB1,aB2,aB3, dBE, cB.wE) ACC8(aB0,aB1,aB2,aB3, dBF, cB.wF)
  ACC8(aB0,aB1,aB2,aB3, dBG, cB.wG) ACC8(aB0,aB1,aB2,aB3, dBH, cB.wH)
  #undef ACC8

  // rare: combo A of either pair is plane (0,0) -> gather from f32 fm
  const float* fmv = fm + (long)v * (262144L * FD) + (q >> 1) * 8;
  if (cA.z00) {
    int px = min(cA.ix0 + (qodd ? 1 : 0), 511);
    long o0 = ((long)cA.iy0 * 512 + px) * FD;
    long o1 = o0 + (long)cA.dy0 * 512 * FD;
    float4 ga = *(const float4*)(fmv + o0);
    float4 gb = *(const float4*)(fmv + o0 + 4);
    float4 ha = *(const float4*)(fmv + o1);
    float4 hb = *(const float4*)(fmv + o1 + 4);
    __half2 hw0 = __float2half2_rn(cA.fwA);
    __half2 hw1 = __float2half2_rn(cA.fwB);
    aA0 = __hfma2(__floats2half2_rn(ga.x, ga.y), hw0, aA0);
    aA1 = __hfma2(__floats2half2_rn(ga.z, ga.w), hw0, aA1);
    aA2 = __hfma2(__floats2half2_rn(gb.x, gb.y), hw0, aA2);
    aA3 = __hfma2(__floats2half2_rn(gb.z, gb.w), hw0, aA3);
    aA0 = __hfma2(__floats2half2_rn(ha.x, ha.y), hw1, aA0);
    aA1 = __hfma2(__floats2half2_rn(ha.z, ha.w), hw1, aA1);
    aA2 = __hfma2(__floats2half2_rn(hb.x, hb.y), hw1, aA2);
    aA3 = __hfma2(__floats2half2_rn(hb.z, hb.w), hw1, aA3);
  }
  if (cB.z00) {
    int px = min(cB.ix0 + (qodd ? 1 : 0), 511);
    long o0 = ((long)cB.iy0 * 512 + px) * FD;
    long o1 = o0 + (long)cB.dy0 * 512 * FD;
    float4 ga = *(const float4*)(fmv + o0);
    float4 gb = *(const float4*)(fmv + o0 + 4);
    float4 ha = *(const float4*)(fmv + o1);
    float4 hb = *(const float4*)(fmv + o1 + 4);
    __half2 hw0 = __float2half2_rn(cB.fwA);
    __half2 hw1 = __float2half2_rn(cB.fwB);
    aB0 = __hfma2(__floats2half2_rn(ga.x, ga.y), hw0, aB0);
    aB1 = __hfma2(__floats2half2_rn(ga.z, ga.w), hw0, aB1);
    aB2 = __hfma2(__floats2half2_rn(gb.x, gb.y), hw0, aB2);
    aB3 = __hfma2(__floats2half2_rn(gb.z, gb.w), hw0, aB3);
    aB0 = __hfma2(__floats2half2_rn(ha.x, ha.y), hw1, aB0);
    aB1 = __hfma2(__floats2half2_rn(ha.z, ha.w), hw1, aB1);
    aB2 = __hfma2(__floats2half2_rn(hb.x, hb.y), hw1, aB2);
    aB3 = __hfma2(__floats2half2_rn(hb.z, hb.w), hw1, aB3);
  }

  // combine the two pixels of the bilinear x-span (lanes q and q^1)
  #define XC(A0, A1, A2, A3) {                                   \
    int x0 = *(int*)&A0, x1 = *(int*)&A1;                        \
    int x2 = *(int*)&A2, x3 = *(int*)&A3;                        \
    int y0 = __shfl_xor(x0, 1), y1 = __shfl_xor(x1, 1);          \
    int y2 = __shfl_xor(x2, 1), y3 = __shfl_xor(x3, 1);          \
    A0 = __hadd2(A0, *(__half2*)&y0); A1 = __hadd2(A1, *(__half2*)&y1); \
    A2 = __hadd2(A2, *(__half2*)&y2); A3 = __hadd2(A3, *(__half2*)&y3); }
  XC(aA0, aA1, aA2, aA3)
  XC(aB0, aB1, aB2, aB3)
  #undef XC

  __half2 sA0 = qodd ? aA2 : aA0;
  __half2 sA1 = qodd ? aA3 : aA1;
  float2 fA0 = __half22float2(sA0);
  float2 fA1 = __half22float2(sA1);
  *(float4*)(out + ((long)nA * NV + v) * FD + q * 4) =
      make_float4(fA0.x, fA0.y, fA1.x, fA1.y);

  __half2 sB0 = qodd ? aB2 : aB0;
  __half2 sB1 = qodd ? aB3 : aB1;
  float2 fB0 = __half22float2(sB0);
  float2 fB1 = __half22float2(sB1);
  *(float4*)(out + ((long)nB * NV + v) * FD + q * 4) =
      make_float4(fB0.x, fB0.y, fB1.x, fB1.y);
}

extern "C" void kernel_launch(void* const* d_in, const int* in_sizes, int n_in,
                              void* d_out, int out_size, void* d_ws, size_t ws_size,
                              hipStream_t stream)
{
  const float* means = (const float*)d_in[0];
  const float* covs  = (const float*)d_in[1];
  const float* fm    = (const float*)d_in[2];
  float* out = (float*)d_out;
  __half* pyr = (__half*)d_ws;
  float4* pl  = (float4*)((char*)d_ws + OFF_PL);

  build_all<<<NV * 256, 256, 0, stream>>>(fm, pyr);
  {
    int tB = NV * 8 * 2040;    // levels 4..6 from 3
    pool_hN<3, 3><<<(tB + 255) / 256, 256, 0, stream>>>(pyr);
    int tC = NV * 4 * 2040;    // level 7 from 6
    pool_hN<6, 1><<<(tC + 255) / 256, 256, 0, stream>>>(pyr);
  }
  {
    dim3 g(1280, 16, 1);       // 1280 covers the largest (128x128) combo
    build_dup<<<g, 256, 0, stream>>>(pyr);
  }
  proj_kernel<<<(NS + 255) / 256, 256, 0, stream>>>(means, covs, pl);

  interp8<<<20480, 256, 0, stream>>>(pl, pyr, fm, out);
}